// Round 2
// baseline (361.025 us; speedup 1.0000x reference)
//
#include <hip/hip_runtime.h>
#include <hip/hip_bf16.h>

#define S_LEN 2048
#define BATCH 2
#define EDIM 1024
#define NHEAD 16
#define DHEAD 64
#define HIDDEN 512
#define SIGD 64
#define KEEP 12           // NUM_HEADS - INACTIVE

typedef __attribute__((ext_vector_type(8))) short bf16x8;
typedef __attribute__((ext_vector_type(4))) float f32x4;

static __device__ __forceinline__ float bf2f(short s) {
  unsigned int u = ((unsigned int)(unsigned short)s) << 16;
  float f; __builtin_memcpy(&f, &u, 4); return f;
}
static __device__ __forceinline__ short f2bf(float f) {
  unsigned int u; __builtin_memcpy(&u, &f, 4);
  u += 0x7fffu + ((u >> 16) & 1u);   // round-to-nearest-even
  return (short)(u >> 16);
}

#if __has_builtin(__builtin_amdgcn_exp2f)
static __device__ __forceinline__ float fexp2(float x) { return __builtin_amdgcn_exp2f(x); }
#else
static __device__ __forceinline__ float fexp2(float x) { return exp2f(x); }
#endif

// async global->LDS, 16B per lane. LDS dest is wave-uniform base + lane*16.
static __device__ __forceinline__ void gl_lds16(const short* g, short* l) {
  __builtin_amdgcn_global_load_lds(
      (const __attribute__((address_space(1))) unsigned int*)g,
      (__attribute__((address_space(3))) unsigned int*)l, 16, 0, 0);
}

// DPP all-reduce across the 16 lanes of a DPP row (= our quad group).
template<int CTRL>
static __device__ __forceinline__ float dpp_movf(float x) {
  return __builtin_bit_cast(float, __builtin_amdgcn_update_dpp(
      0, __builtin_bit_cast(int, x), CTRL, 0xF, 0xF, true));
}
static __device__ __forceinline__ float row_max16(float v) {
  v = fmaxf(v, dpp_movf<0x128>(v));   // row_ror:8
  v = fmaxf(v, dpp_movf<0x124>(v));   // row_ror:4
  v = fmaxf(v, dpp_movf<0x122>(v));   // row_ror:2
  v = fmaxf(v, dpp_movf<0x121>(v));   // row_ror:1
  return v;
}
static __device__ __forceinline__ float row_sum16(float v) {
  v += dpp_movf<0x128>(v);
  v += dpp_movf<0x124>(v);
  v += dpp_movf<0x122>(v);
  v += dpp_movf<0x121>(v);
  return v;
}

// ---------------- kernel 1: ALL dtype conversions in one launch ----------------
// [0,4096): query hi/lo split. [4096,4608): inf1_w hi/lo split.
// [4608,5632) Wq, [5632,6656) Wk, [6656,7680) Wv, [7680,8704) Wo (plain bf16).
__global__ __launch_bounds__(256) void cvt_all(
    const float* __restrict__ query, const float* __restrict__ inf1_w,
    const float* __restrict__ qw, const float* __restrict__ kw,
    const float* __restrict__ vw, const float* __restrict__ ow,
    short* __restrict__ qh, short* __restrict__ ql,
    short* __restrict__ w1h, short* __restrict__ w1l,
    short* __restrict__ Wq, short* __restrict__ Wk,
    short* __restrict__ Wv, short* __restrict__ Wo)
{
  int blk = blockIdx.x;
  if (blk < 4608) {              // split sections
    const float* in; short *oh, *ol; int i;
    if (blk < 4096) { in = query;  oh = qh;  ol = ql;  i = (blk * 256 + threadIdx.x) * 4; }
    else            { in = inf1_w; oh = w1h; ol = w1l; i = ((blk - 4096) * 256 + threadIdx.x) * 4; }
    float4 f = *(const float4*)(in + i);
    union { short s[4]; uint2 v; } uh, ul;
    float x[4] = {f.x, f.y, f.z, f.w};
    #pragma unroll
    for (int u = 0; u < 4; ++u) {
      short h = f2bf(x[u]);
      uh.s[u] = h;
      ul.s[u] = f2bf(x[u] - bf2f(h));
    }
    *(uint2*)(oh + i) = uh.v;
    *(uint2*)(ol + i) = ul.v;
  } else {                       // plain bf16 sections (1024 blocks each)
    int t = blk - 4608;
    int mat = t >> 10, sub = t & 1023;
    const float* in = (mat == 0) ? qw : (mat == 1) ? kw : (mat == 2) ? vw : ow;
    short* out      = (mat == 0) ? Wq : (mat == 1) ? Wk : (mat == 2) ? Wv : Wo;
    int i = (sub * 256 + threadIdx.x) * 4;
    float4 f = *(const float4*)(in + i);
    union { short s[4]; uint2 v; } u;
    u.s[0] = f2bf(f.x); u.s[1] = f2bf(f.y); u.s[2] = f2bf(f.z); u.s[3] = f2bf(f.w);
    *(uint2*)(out + i) = u.v;
  }
}

// ---------------- m97-style 128x128 GEMM body (smem passed in) ----------------
template<bool F32OUT>
static __device__ __forceinline__ void gemm128_body(
    short* smem,
    const short* __restrict__ A, const short* __restrict__ B,
    const float* __restrict__ bias, void* __restrict__ outv,
    int row0, int col0, float scale)
{
  short* As = smem;              // 128*32
  short* Bs = smem + 128*32;     // 128*32
  const int tid  = threadIdx.x;
  const int wave = tid >> 6, lane = tid & 63;
  const int quad = lane >> 4, l16 = lane & 15;
  const int wr = wave >> 1, wc = wave & 1;
  const int lr = lane >> 2, lc8 = (lane & 3) * 8;

  const short* gA = A + (size_t)(row0 + wave*16 + lr) * EDIM + lc8;
  const short* gB = B + (size_t)(col0 + wave*16 + lr) * EDIM + lc8;
  short* lA = As + wave*512;
  short* lB = Bs + wave*512;

  f32x4 acc[4][4] = {};
  gl_lds16(gA, lA);  gl_lds16(gA + 64*EDIM, lA + 64*32);
  gl_lds16(gB, lB);  gl_lds16(gB + 64*EDIM, lB + 64*32);

  for (int k0 = 0; k0 < EDIM; k0 += 32) {
    __syncthreads();
    bf16x8 af[4], bfr[4];
    #pragma unroll
    for (int i = 0; i < 4; ++i)
      af[i] = *(const bf16x8*)&As[(wr*64 + i*16 + l16)*32 + quad*8];
    #pragma unroll
    for (int j = 0; j < 4; ++j)
      bfr[j] = *(const bf16x8*)&Bs[(wc*64 + j*16 + l16)*32 + quad*8];
    __syncthreads();
    if (k0 + 32 < EDIM) {
      const short* gA2 = gA + k0 + 32;
      const short* gB2 = gB + k0 + 32;
      gl_lds16(gA2, lA);  gl_lds16(gA2 + 64*EDIM, lA + 64*32);
      gl_lds16(gB2, lB);  gl_lds16(gB2 + 64*EDIM, lB + 64*32);
    }
    #pragma unroll
    for (int i = 0; i < 4; ++i)
      #pragma unroll
      for (int j = 0; j < 4; ++j)
        acc[i][j] = __builtin_amdgcn_mfma_f32_16x16x32_bf16(af[i], bfr[j], acc[i][j], 0, 0, 0);
  }
  #pragma unroll
  for (int j = 0; j < 4; ++j) {
    int col = col0 + wc*64 + j*16 + l16;
    float bv = bias[col];
    #pragma unroll
    for (int i = 0; i < 4; ++i) {
      int rowb = row0 + wr*64 + i*16 + quad*4;
      #pragma unroll
      for (int r = 0; r < 4; ++r) {
        float v = (acc[i][j][r] + bv) * scale;
        if constexpr (F32OUT) {
          ((float*)outv)[(size_t)(rowb + r) * EDIM + col] = v;
        } else {
          ((short*)outv)[(size_t)(rowb + r) * EDIM + col] = f2bf(v);
        }
      }
    }
  }
}

// t1 body: 128x64 tile, hi/lo-split (3 MFMAs, fp32-accurate), relu -> T1 fp32.
static __device__ __forceinline__ void gemm_t1_body(
    short* smem,
    const short* __restrict__ Agh, const short* __restrict__ Agl,
    const short* __restrict__ Bgh, const short* __restrict__ Bgl,
    const float* __restrict__ bias, float* __restrict__ T1,
    int row0, int col0)
{
  short* Ah = smem;              // 128*32
  short* Al = smem + 4096;      // 128*32
  short* Bh = smem + 8192;      // 64*32
  short* Bl = smem + 10240;     // 64*32
  const int tid  = threadIdx.x;
  const int wave = tid >> 6, lane = tid & 63;
  const int quad = lane >> 4, l16 = lane & 15;
  const int wr = wave >> 1, wc = wave & 1;
  const int lr = lane >> 2, lc8 = (lane & 3) * 8;

  const short* gAh = Agh + (size_t)(row0 + wave*16 + lr) * EDIM + lc8;
  const short* gAl = Agl + (size_t)(row0 + wave*16 + lr) * EDIM + lc8;
  const short* gBh = Bgh + (size_t)(col0 + wave*16 + lr) * EDIM + lc8;
  const short* gBl = Bgl + (size_t)(col0 + wave*16 + lr) * EDIM + lc8;
  short* lAh = Ah + wave*512;  short* lAl = Al + wave*512;
  short* lBh = Bh + wave*512;  short* lBl = Bl + wave*512;

  f32x4 acc[4][2] = {};
  gl_lds16(gAh, lAh);  gl_lds16(gAh + 64*EDIM, lAh + 64*32);
  gl_lds16(gAl, lAl);  gl_lds16(gAl + 64*EDIM, lAl + 64*32);
  gl_lds16(gBh, lBh);  gl_lds16(gBl, lBl);

  for (int k0 = 0; k0 < EDIM; k0 += 32) {
    __syncthreads();
    bf16x8 ah[4], al[4], bh[2], bl[2];
    #pragma unroll
    for (int i = 0; i < 4; ++i) {
      ah[i] = *(const bf16x8*)&Ah[(wr*64 + i*16 + l16)*32 + quad*8];
      al[i] = *(const bf16x8*)&Al[(wr*64 + i*16 + l16)*32 + quad*8];
    }
    #pragma unroll
    for (int j = 0; j < 2; ++j) {
      bh[j] = *(const bf16x8*)&Bh[(wc*32 + j*16 + l16)*32 + quad*8];
      bl[j] = *(const bf16x8*)&Bl[(wc*32 + j*16 + l16)*32 + quad*8];
    }
    __syncthreads();
    if (k0 + 32 < EDIM) {
      const short* p;
      p = gAh + k0 + 32;  gl_lds16(p, lAh);  gl_lds16(p + 64*EDIM, lAh + 64*32);
      p = gAl + k0 + 32;  gl_lds16(p, lAl);  gl_lds16(p + 64*EDIM, lAl + 64*32);
      gl_lds16(gBh + k0 + 32, lBh);  gl_lds16(gBl + k0 + 32, lBl);
    }
    #pragma unroll
    for (int i = 0; i < 4; ++i)
      #pragma unroll
      for (int j = 0; j < 2; ++j) {
        acc[i][j] = __builtin_amdgcn_mfma_f32_16x16x32_bf16(ah[i], bh[j], acc[i][j], 0, 0, 0);
        acc[i][j] = __builtin_amdgcn_mfma_f32_16x16x32_bf16(ah[i], bl[j], acc[i][j], 0, 0, 0);
        acc[i][j] = __builtin_amdgcn_mfma_f32_16x16x32_bf16(al[i], bh[j], acc[i][j], 0, 0, 0);
      }
  }
  #pragma unroll
  for (int j = 0; j < 2; ++j) {
    int col = col0 + wc*32 + j*16 + l16;
    float bv = bias[col];
    #pragma unroll
    for (int i = 0; i < 4; ++i) {
      int rowb = row0 + wr*64 + i*16 + quad*4;
      #pragma unroll
      for (int r = 0; r < 4; ++r)
        T1[(size_t)(rowb + r) * HIDDEN + col] = fmaxf(acc[i][j][r] + bv, 0.0f);
    }
  }
}

// ---------------- kernel 2: t1 GEMM + QKV GEMM, interleaved 1:3 ----------------
__global__ __launch_bounds__(256) void mega_gemm1(
    const short* __restrict__ qh, const short* __restrict__ ql,
    const short* __restrict__ w1h, const short* __restrict__ w1l,
    const float* __restrict__ inf1_b, float* __restrict__ T1,
    const short* __restrict__ Wq, const short* __restrict__ Wk,
    const short* __restrict__ Wv,
    const float* __restrict__ qb, const float* __restrict__ kb,
    const float* __restrict__ vb,
    short* __restrict__ Qp, short* __restrict__ Kp, short* __restrict__ Vp)
{
  __shared__ __attribute__((aligned(16))) short smem[12288];   // 24 KB union
  int blk = blockIdx.x;
  if ((blk & 3) == 3) {
    int id = blk >> 2;                         // [0,256)
    gemm_t1_body(smem, qh, ql, w1h, w1l, inf1_b, T1,
                 (id & 31) * 128, (id >> 5) * 64);
  } else {
    int id = (blk >> 2) * 3 + (blk & 3);       // [0,768)
    int row0 = (id & 31) * 128;
    int rest = id >> 5;                        // [0,24)
    int mat = rest >> 3, cb = rest & 7;
    const short* B   = (mat == 0) ? Wq : (mat == 1) ? Wk : Wv;
    const float* bia = (mat == 0) ? qb : (mat == 1) ? kb : vb;
    short* out       = (mat == 0) ? Qp : (mat == 1) ? Kp : Vp;
    // q scale folds D^-0.5 * log2(e) (flash softmax runs in exp2 domain)
    float scale      = (mat == 0) ? 0.18033688011112042f : 1.0f;
    gemm128_body<false>(smem, qh, B, bia, (void*)out, row0, cb * 128, scale);
  }
}

// ---------------- kernel 3: head-mask + V-transpose in one launch ----------------
__global__ __launch_bounds__(256) void mid_kernel(
    const float* __restrict__ T1, const float* __restrict__ inf2_w,
    const float* __restrict__ inf2_b, const float* __restrict__ head_sig,
    float* __restrict__ maskbuf,
    const short* __restrict__ Vp, short* __restrict__ VT)
{
  __shared__ __attribute__((aligned(16))) float fsm[16*HIDDEN + 16*SIGD + 16*NHEAD];
  int blk = blockIdx.x;
  const int tid = threadIdx.x;
  if (blk < 256) {
    // ---- head mask: t2 = t1 @ inf2_w^T + b ; s = t2 @ head_sig^T ; top-12 ----
    float (*t1s)[HIDDEN] = (float(*)[HIDDEN])fsm;
    float (*t2s)[SIGD]   = (float(*)[SIGD])(fsm + 16*HIDDEN);
    float (*ss)[NHEAD]   = (float(*)[NHEAD])(fsm + 16*HIDDEN + 16*SIGD);
    const int tok0 = blk * 16;
    {
      int row = tid >> 4, c0 = (tid & 15) * 32;
      const float* src = T1 + (size_t)(tok0 + row) * HIDDEN + c0;
      #pragma unroll
      for (int u = 0; u < 8; ++u)
        *(float4*)&t1s[row][c0 + u*4] = *(const float4*)(src + u*4);
    }
    __syncthreads();
    #pragma unroll
    for (int it = 0; it < 4; ++it) {
      int idx = tid + it * 256;
      int tok = idx >> 6, j = idx & 63;
      const float4* w4 = (const float4*)(inf2_w + (size_t)j * HIDDEN);
      const float4* t4 = (const float4*)(&t1s[tok][0]);
      float a = inf2_b[j];
      for (int k = 0; k < HIDDEN/4; ++k) {
        float4 wv = w4[k], tv = t4[k];
        a += tv.x*wv.x + tv.y*wv.y + tv.z*wv.z + tv.w*wv.w;
      }
      t2s[tok][j] = a;
    }
    __syncthreads();
    {
      int tok = tid >> 4, h = tid & 15;
      float a = 0.f;
      for (int d = 0; d < SIGD; ++d) a += t2s[tok][d] * head_sig[h*SIGD + d];
      ss[tok][h] = a;
    }
    __syncthreads();
    {
      int tok = tid >> 4, h = tid & 15;
      float sv = ss[tok][h];
      int cnt = 0;
      #pragma unroll
      for (int j = 0; j < NHEAD; ++j) cnt += (ss[tok][j] > sv) ? 1 : 0;
      int gt = tok0 + tok;
      int s = gt >> 1, b = gt & 1;             // token row = s*B + b
      maskbuf[((size_t)(b*NHEAD + h)) * S_LEN + s] = (cnt < KEEP) ? 1.0f : 0.0f;
    }
  } else {
    // ---- V transpose: Vp (token-major) -> VT[(b*16+h)*64+d][S_LEN] ----
    short (*tile)[72] = (short(*)[72])fsm;
    int t = blk - 256;                          // [0,1024)
    const int s0 = (t & 31) * 64, e0 = ((t >> 5) & 15) * 64, b = t >> 9;
    {
      int sr = tid >> 2, ec = (tid & 3) * 16;
      const short* src = Vp + (size_t)(s0 + sr) * 2048 + b * 1024 + e0 + ec;
      *(uint4*)&tile[sr][ec]     = *(const uint4*)src;
      *(uint4*)&tile[sr][ec + 8] = *(const uint4*)(src + 8);
    }
    __syncthreads();
    {
      int er = tid >> 2, sc = (tid & 3) * 16;
      unsigned pack[8];
      #pragma unroll
      for (int u = 0; u < 8; ++u) {
        unsigned lo = (unsigned short)tile[sc + 2*u][er];
        unsigned hi = (unsigned short)tile[sc + 2*u + 1][er];
        pack[u] = lo | (hi << 16);
      }
      short* dst = VT + (size_t)(b * 1024 + e0 + er) * 2048 + s0 + sc;
      *(uint4*)(dst)     = *(uint4*)&pack[0];
      *(uint4*)(dst + 8) = *(uint4*)&pack[4];
    }
  }
}

// ---------------- kernel 4: flash attention (exp2 domain) ----------------
// v3: KV=128 (R0 amortization) + conflict-free stride family from R1 (all LDS
// row strides 68 shorts = word-stride 2 mod 32; 128-wide buffers split into
// two 64-col banks) + T14 reg-prefetch (issue-early/write-late) + setprio +
// defer-max (skip alpha/rescale when all rows within 2^8 of running max).
// LDS = 3 x 17408 = 52224 B -> 3 blocks/CU.
__global__ __launch_bounds__(256) void flash_attn(
    short* QpOg, const short* __restrict__ Kp, const short* __restrict__ VT,
    const float* __restrict__ maskbuf)
{
  __shared__ __attribute__((aligned(16))) short Ks[128][68];    // 17408 B
  __shared__ __attribute__((aligned(16))) short Vt[2][64][68];  // 17408 B (rows=d, two 64-kv banks)
  __shared__ __attribute__((aligned(16))) short uni[8704];      // Qstage 64x68 | Ps[w][2][16][68]
  const int bh = blockIdx.x;
  const int b = bh >> 4, h = bh & 15;
  const int q0 = blockIdx.y * 64;
  const int tid = threadIdx.x;
  const int wave = tid >> 6, lane = tid & 63;
  const int quad = lane >> 4, l16 = lane & 15;
  const size_t colbase = (size_t)b * EDIM + h * DHEAD;
  const size_t rstride = (size_t)BATCH * EDIM;   // 2048

  const int r4 = tid >> 2, c16 = (tid & 3) * 16;
  const short* gK = Kp + (size_t)r4 * rstride + colbase + c16;   // +kv0*rstride per tile
  const short* gV = VT + (size_t)(bh * 64 + r4) * S_LEN + c16;   // +kv0 per tile

  {  // stage Q into uni, read fragments to regs
    const short* src = QpOg + (size_t)(q0 + r4) * rstride + colbase + c16;
    *(uint4*)&uni[r4*68 + c16]     = *(const uint4*)src;
    *(uint4*)&uni[r4*68 + c16 + 8] = *(const uint4*)(src + 8);
  }
  __syncthreads();
  bf16x8 aq0 = *(const bf16x8*)&uni[(wave*16 + l16)*68 + quad*8];
  bf16x8 aq1 = *(const bf16x8*)&uni[(wave*16 + l16)*68 + 32 + quad*8];
  short* Psw = &uni[wave * 2176];        // per-wave [2 halves][16 rows][68]

  // prefetch tile 0 into registers (K: rows r4 and r4+64; V: kv-halves 0/1)
  uint4 ka0 = *(const uint4*)(gK);
  uint4 ka1 = *(const uint4*)(gK + 8);
  uint4 kb0 = *(const uint4*)(gK + 64*rstride);
  uint4 kb1 = *(const uint4*)(gK + 64*rstride + 8);
  uint4 va0 = *(const uint4*)(gV);
  uint4 va1 = *(const uint4*)(gV + 8);
  uint4 vb0 = *(const uint4*)(gV + 64);
  uint4 vb1 = *(const uint4*)(gV + 72);

  float m_i[4], l_i[4];
  f32x4 oacc[4];
  #pragma unroll
  for (int r = 0; r < 4; ++r) { m_i[r] = -1e30f; l_i[r] = 0.f; }
  #pragma unroll
  for (int dt = 0; dt < 4; ++dt) oacc[dt] = f32x4{0.f, 0.f, 0.f, 0.f};

  for (int kv0 = 0; kv0 < S_LEN; kv0 += 128) {
    __syncthreads();              // prev tile's LDS reads complete
    *(uint4*)&Ks[r4][c16]        = ka0;
    *(uint4*)&Ks[r4][c16 + 8]    = ka1;
    *(uint4*)&Ks[r4+64][c16]     = kb0;
    *(uint4*)&Ks[r4+64][c16 + 8] = kb1;
    *(uint4*)&Vt[0][r4][c16]     = va0;
    *(uint4*)&Vt[0][r4][c16 + 8] = va1;
    *(uint4*)&Vt[1][r4][c16]     = vb0;
    *(uint4*)&Vt[1][r4][c16 + 8] = vb1;
    __syncthreads();
    if (kv0 + 128 < S_LEN) {      // issue next-tile loads; drain under compute
      const short* nK = gK + (size_t)(kv0 + 128) * rstride;
      const short* nV = gV + (kv0 + 128);
      ka0 = *(const uint4*)nK;
      ka1 = *(const uint4*)(nK + 8);
      kb0 = *(const uint4*)(nK + 64*rstride);
      kb1 = *(const uint4*)(nK + 64*rstride + 8);
      va0 = *(const uint4*)nV;
      va1 = *(const uint4*)(nV + 8);
      vb0 = *(const uint4*)(nV + 64);
      vb1 = *(const uint4*)(nV + 72);
    }
    f32x4 sacc[8];
    #pragma unroll
    for (int c = 0; c < 8; ++c) sacc[c] = f32x4{0.f, 0.f, 0.f, 0.f};
    __builtin_amdgcn_s_setprio(1);
    #pragma unroll
    for (int c = 0; c < 8; ++c) {
      bf16x8 b0 = *(const bf16x8*)&Ks[c*16 + l16][quad*8];
      bf16x8 b1 = *(const bf16x8*)&Ks[c*16 + l16][32 + quad*8];
      sacc[c] = __builtin_amdgcn_mfma_f32_16x16x32_bf16(aq0, b0, sacc[c], 0, 0, 0);
      sacc[c] = __builtin_amdgcn_mfma_f32_16x16x32_bf16(aq1, b1, sacc[c], 0, 0, 0);
    }
    __builtin_amdgcn_s_setprio(0);
    #pragma unroll
    for (int r = 0; r < 4; ++r) {
      float vmax = fmaxf(fmaxf(fmaxf(sacc[0][r], sacc[1][r]),
                               fmaxf(sacc[2][r], sacc[3][r])),
                         fmaxf(fmaxf(sacc[4][r], sacc[5][r]),
                               fmaxf(sacc[6][r], sacc[7][r])));
      vmax = row_max16(vmax);
      // defer-max: only rescale when some row grew by > 2^8 (exp2 domain).
      if (!__all(vmax <= m_i[r] + 8.0f)) {
        float mnew = fmaxf(m_i[r], vmax);
        float alpha = fexp2(m_i[r] - mnew);
        l_i[r] *= alpha;
        #pragma unroll
        for (int dt = 0; dt < 4; ++dt) oacc[dt][r] *= alpha;
        m_i[r] = mnew;
      }
      float rsum = 0.f;
      short* prow = &Psw[(quad*4 + r)*68 + l16];
      #pragma unroll
      for (int p = 0; p < 4; ++p) {
        float ea = fexp2(sacc[2*p][r]   - m_i[r]);
        float eb = fexp2(sacc[2*p+1][r] - m_i[r]);
        unsigned pk = __builtin_amdgcn_perm(
            __builtin_bit_cast(unsigned, eb),
            __builtin_bit_cast(unsigned, ea), 0x07060302u);
        short* pr = prow + (p >> 1) * 1088;          // kv-half bank
        pr[(2*(p & 1))*16]     = (short)(pk & 0xffffu);
        pr[(2*(p & 1) + 1)*16] = (short)(pk >> 16);
        rsum += ea + eb;
      }
      rsum = row_sum16(rsum);
      l_i[r] += rsum;
    }
    asm volatile("s_waitcnt lgkmcnt(0)" ::: "memory");   // Ps visible (same wave)
    __builtin_amdgcn_s_setprio(1);
    #pragma unroll
    for (int ks = 0; ks < 4; ++ks) {
      bf16x8 ap = *(const bf16x8*)&Psw[(ks>>1)*1088 + l16*68 + (ks&1)*32 + quad*8];
      #pragma unroll
      for (int dt = 0; dt < 4; ++dt) {
        bf16x8 bb = *(const bf16x8*)&Vt[ks>>1][dt*16 + l16][(ks&1)*32 + quad*8];
        oacc[dt] = __builtin_amdgcn_mfma_f32_16x16x32_bf16(ap, bb, oacc[dt], 0, 0, 0);
      }
    }
    __builtin_amdgcn_s_setprio(0);
  }
  #pragma unroll
  for (int r = 0; r < 4; ++r) {
    int s = q0 + wave*16 + quad*4 + r;
    float mk = maskbuf[((size_t)(b*NHEAD + h)) * S_LEN + s];
    float scale = mk / l_i[r];
    short* dst = QpOg + (size_t)s * rstride + colbase;
    #pragma unroll
    for (int dt = 0; dt < 4; ++dt)
      dst[dt*16 + l16] = f2bf(oacc[dt][r] * scale);
  }
}

// ---------------- kernel 5: out projection ----------------
__global__ __launch_bounds__(256) void gemm_out(
    const short* __restrict__ A, const short* __restrict__ W,
    const float* __restrict__ bias, float* __restrict__ out)
{
  __shared__ __attribute__((aligned(16))) short smem[8192];
  gemm128_body<true>(smem, A, W, bias, (void*)out,
                     blockIdx.x * 128, blockIdx.y * 128, 1.0f);
}

extern "C" void kernel_launch(void* const* d_in, const int* in_sizes, int n_in,
                              void* d_out, int out_size, void* d_ws, size_t ws_size,
                              hipStream_t stream)
{
  const float* query   = (const float*)d_in[0];
  const float* q_w     = (const float*)d_in[1];
  const float* q_b     = (const float*)d_in[2];
  const float* k_w     = (const float*)d_in[3];
  const float* k_b     = (const float*)d_in[4];
  const float* v_w     = (const float*)d_in[5];
  const float* v_b     = (const float*)d_in[6];
  const float* out_w   = (const float*)d_in[7];
  const float* out_b   = (const float*)d_in[8];
  const float* inf1_w  = (const float*)d_in[9];
  const float* inf1_b  = (const float*)d_in[10];
  const float* inf2_w  = (const float*)d_in[11];
  const float* inf2_b  = (const float*)d_in[12];
  const float* head_sig= (const float*)d_in[13];

  char* ws = (char*)d_ws;
  short* qh      = (short*)(ws);
  short* VTb     = (short*)(ws);
  short* ql      = (short*)(ws + (size_t)( 8u<<20));
  float* maskbuf = (float*)(ws + (size_t)( 8u<<20));
  short* Qp      = (short*)(ws + (size_t)(16u<<20));
  short* Kp      = (short*)(ws + (size_t)(24u<<20));
  short* Vp      = (short*)(ws + (size_t)(32u<<20));
  short* Wo      = (short*)(ws + (size_t)(40u<<20));
  char* ob = (char*)d_out;
  float* T1  = (float*)(ob);
  short* w1h = (short*)(ob + (size_t)( 8u<<20));
  short* w1l = (short*)(ob + (size_t)( 9u<<20));
  short* Wq  = (short*)(ob + (size_t)(10u<<20));
  short* Wk  = (short*)(ob + (size_t)(12u<<20));
  short* Wv  = (short*)(ob + (size_t)(14u<<20));
  float* out = (float*)d_out;

  dim3 blk(256);
  cvt_all<<<dim3(8704), blk, 0, stream>>>(query, inf1_w, q_w, k_w, v_w, out_w,
                                          qh, ql, w1h, w1l, Wq, Wk, Wv, Wo);
  mega_gemm1<<<dim3(1024), blk, 0, stream>>>(qh, ql, w1h, w1l, inf1_b, T1,
                                             Wq, Wk, Wv, q_b, k_b, v_b, Qp, Kp, Vp);
  mid_kernel<<<dim3(1280), blk, 0, stream>>>(T1, inf2_w, inf2_b, head_sig, maskbuf,
                                             Vp, VTb);
  flash_attn<<<dim3(32, 32), blk, 0, stream>>>(Qp, Kp, VTb, maskbuf);
  gemm_out<<<dim3(32, 8), blk, 0, stream>>>(Qp, Wo, out_b, out);
}

// Round 3
// 354.077 us; speedup vs baseline: 1.0196x; 1.0196x over previous
//
#include <hip/hip_runtime.h>
#include <hip/hip_bf16.h>

#define S_LEN 2048
#define BATCH 2
#define EDIM 1024
#define NHEAD 16
#define DHEAD 64
#define HIDDEN 512
#define SIGD 64
#define KEEP 12           // NUM_HEADS - INACTIVE

typedef __attribute__((ext_vector_type(8))) short bf16x8;
typedef __attribute__((ext_vector_type(4))) float f32x4;

static __device__ __forceinline__ float bf2f(short s) {
  unsigned int u = ((unsigned int)(unsigned short)s) << 16;
  float f; __builtin_memcpy(&f, &u, 4); return f;
}
static __device__ __forceinline__ short f2bf(float f) {
  unsigned int u; __builtin_memcpy(&u, &f, 4);
  u += 0x7fffu + ((u >> 16) & 1u);   // round-to-nearest-even
  return (short)(u >> 16);
}

#if __has_builtin(__builtin_amdgcn_exp2f)
static __device__ __forceinline__ float fexp2(float x) { return __builtin_amdgcn_exp2f(x); }
#else
static __device__ __forceinline__ float fexp2(float x) { return exp2f(x); }
#endif

// async global->LDS, 16B per lane. LDS dest is wave-uniform base + lane*16.
static __device__ __forceinline__ void gl_lds16(const short* g, short* l) {
  __builtin_amdgcn_global_load_lds(
      (const __attribute__((address_space(1))) unsigned int*)g,
      (__attribute__((address_space(3))) unsigned int*)l, 16, 0, 0);
}

// DPP all-reduce across the 16 lanes of a DPP row (= our quad group).
template<int CTRL>
static __device__ __forceinline__ float dpp_movf(float x) {
  return __builtin_bit_cast(float, __builtin_amdgcn_update_dpp(
      0, __builtin_bit_cast(int, x), CTRL, 0xF, 0xF, true));
}
static __device__ __forceinline__ float row_max16(float v) {
  v = fmaxf(v, dpp_movf<0x128>(v));   // row_ror:8
  v = fmaxf(v, dpp_movf<0x124>(v));   // row_ror:4
  v = fmaxf(v, dpp_movf<0x122>(v));   // row_ror:2
  v = fmaxf(v, dpp_movf<0x121>(v));   // row_ror:1
  return v;
}
static __device__ __forceinline__ float row_sum16(float v) {
  v += dpp_movf<0x128>(v);
  v += dpp_movf<0x124>(v);
  v += dpp_movf<0x122>(v);
  v += dpp_movf<0x121>(v);
  return v;
}

// ---------------- kernel 1: ALL dtype conversions in one launch ----------------
// [0,4096): query hi/lo split. [4096,4608): inf1_w hi/lo split.
// [4608,5632) Wq, [5632,6656) Wk, [6656,7680) Wv, [7680,8704) Wo (plain bf16).
__global__ __launch_bounds__(256) void cvt_all(
    const float* __restrict__ query, const float* __restrict__ inf1_w,
    const float* __restrict__ qw, const float* __restrict__ kw,
    const float* __restrict__ vw, const float* __restrict__ ow,
    short* __restrict__ qh, short* __restrict__ ql,
    short* __restrict__ w1h, short* __restrict__ w1l,
    short* __restrict__ Wq, short* __restrict__ Wk,
    short* __restrict__ Wv, short* __restrict__ Wo)
{
  int blk = blockIdx.x;
  if (blk < 4608) {              // split sections
    const float* in; short *oh, *ol; int i;
    if (blk < 4096) { in = query;  oh = qh;  ol = ql;  i = (blk * 256 + threadIdx.x) * 4; }
    else            { in = inf1_w; oh = w1h; ol = w1l; i = ((blk - 4096) * 256 + threadIdx.x) * 4; }
    float4 f = *(const float4*)(in + i);
    union { short s[4]; uint2 v; } uh, ul;
    float x[4] = {f.x, f.y, f.z, f.w};
    #pragma unroll
    for (int u = 0; u < 4; ++u) {
      short h = f2bf(x[u]);
      uh.s[u] = h;
      ul.s[u] = f2bf(x[u] - bf2f(h));
    }
    *(uint2*)(oh + i) = uh.v;
    *(uint2*)(ol + i) = ul.v;
  } else {                       // plain bf16 sections (1024 blocks each)
    int t = blk - 4608;
    int mat = t >> 10, sub = t & 1023;
    const float* in = (mat == 0) ? qw : (mat == 1) ? kw : (mat == 2) ? vw : ow;
    short* out      = (mat == 0) ? Wq : (mat == 1) ? Wk : (mat == 2) ? Wv : Wo;
    int i = (sub * 256 + threadIdx.x) * 4;
    float4 f = *(const float4*)(in + i);
    union { short s[4]; uint2 v; } u;
    u.s[0] = f2bf(f.x); u.s[1] = f2bf(f.y); u.s[2] = f2bf(f.z); u.s[3] = f2bf(f.w);
    *(uint2*)(out + i) = u.v;
  }
}

// ---------------- m97-style 128x128 GEMM body (smem passed in) ----------------
template<bool F32OUT>
static __device__ __forceinline__ void gemm128_body(
    short* smem,
    const short* __restrict__ A, const short* __restrict__ B,
    const float* __restrict__ bias, void* __restrict__ outv,
    int row0, int col0, float scale)
{
  short* As = smem;              // 128*32
  short* Bs = smem + 128*32;     // 128*32
  const int tid  = threadIdx.x;
  const int wave = tid >> 6, lane = tid & 63;
  const int quad = lane >> 4, l16 = lane & 15;
  const int wr = wave >> 1, wc = wave & 1;
  const int lr = lane >> 2, lc8 = (lane & 3) * 8;

  const short* gA = A + (size_t)(row0 + wave*16 + lr) * EDIM + lc8;
  const short* gB = B + (size_t)(col0 + wave*16 + lr) * EDIM + lc8;
  short* lA = As + wave*512;
  short* lB = Bs + wave*512;

  f32x4 acc[4][4] = {};
  gl_lds16(gA, lA);  gl_lds16(gA + 64*EDIM, lA + 64*32);
  gl_lds16(gB, lB);  gl_lds16(gB + 64*EDIM, lB + 64*32);

  for (int k0 = 0; k0 < EDIM; k0 += 32) {
    __syncthreads();
    bf16x8 af[4], bfr[4];
    #pragma unroll
    for (int i = 0; i < 4; ++i)
      af[i] = *(const bf16x8*)&As[(wr*64 + i*16 + l16)*32 + quad*8];
    #pragma unroll
    for (int j = 0; j < 4; ++j)
      bfr[j] = *(const bf16x8*)&Bs[(wc*64 + j*16 + l16)*32 + quad*8];
    __syncthreads();
    if (k0 + 32 < EDIM) {
      const short* gA2 = gA + k0 + 32;
      const short* gB2 = gB + k0 + 32;
      gl_lds16(gA2, lA);  gl_lds16(gA2 + 64*EDIM, lA + 64*32);
      gl_lds16(gB2, lB);  gl_lds16(gB2 + 64*EDIM, lB + 64*32);
    }
    #pragma unroll
    for (int i = 0; i < 4; ++i)
      #pragma unroll
      for (int j = 0; j < 4; ++j)
        acc[i][j] = __builtin_amdgcn_mfma_f32_16x16x32_bf16(af[i], bfr[j], acc[i][j], 0, 0, 0);
  }
  #pragma unroll
  for (int j = 0; j < 4; ++j) {
    int col = col0 + wc*64 + j*16 + l16;
    float bv = bias[col];
    #pragma unroll
    for (int i = 0; i < 4; ++i) {
      int rowb = row0 + wr*64 + i*16 + quad*4;
      #pragma unroll
      for (int r = 0; r < 4; ++r) {
        float v = (acc[i][j][r] + bv) * scale;
        if constexpr (F32OUT) {
          ((float*)outv)[(size_t)(rowb + r) * EDIM + col] = v;
        } else {
          ((short*)outv)[(size_t)(rowb + r) * EDIM + col] = f2bf(v);
        }
      }
    }
  }
}

// t1 body: 128x64 tile, hi/lo-split (3 MFMAs, fp32-accurate), relu -> T1 fp32.
static __device__ __forceinline__ void gemm_t1_body(
    short* smem,
    const short* __restrict__ Agh, const short* __restrict__ Agl,
    const short* __restrict__ Bgh, const short* __restrict__ Bgl,
    const float* __restrict__ bias, float* __restrict__ T1,
    int row0, int col0)
{
  short* Ah = smem;              // 128*32
  short* Al = smem + 4096;      // 128*32
  short* Bh = smem + 8192;      // 64*32
  short* Bl = smem + 10240;     // 64*32
  const int tid  = threadIdx.x;
  const int wave = tid >> 6, lane = tid & 63;
  const int quad = lane >> 4, l16 = lane & 15;
  const int wr = wave >> 1, wc = wave & 1;
  const int lr = lane >> 2, lc8 = (lane & 3) * 8;

  const short* gAh = Agh + (size_t)(row0 + wave*16 + lr) * EDIM + lc8;
  const short* gAl = Agl + (size_t)(row0 + wave*16 + lr) * EDIM + lc8;
  const short* gBh = Bgh + (size_t)(col0 + wave*16 + lr) * EDIM + lc8;
  const short* gBl = Bgl + (size_t)(col0 + wave*16 + lr) * EDIM + lc8;
  short* lAh = Ah + wave*512;  short* lAl = Al + wave*512;
  short* lBh = Bh + wave*512;  short* lBl = Bl + wave*512;

  f32x4 acc[4][2] = {};
  gl_lds16(gAh, lAh);  gl_lds16(gAh + 64*EDIM, lAh + 64*32);
  gl_lds16(gAl, lAl);  gl_lds16(gAl + 64*EDIM, lAl + 64*32);
  gl_lds16(gBh, lBh);  gl_lds16(gBl, lBl);

  for (int k0 = 0; k0 < EDIM; k0 += 32) {
    __syncthreads();
    bf16x8 ah[4], al[4], bh[2], bl[2];
    #pragma unroll
    for (int i = 0; i < 4; ++i) {
      ah[i] = *(const bf16x8*)&Ah[(wr*64 + i*16 + l16)*32 + quad*8];
      al[i] = *(const bf16x8*)&Al[(wr*64 + i*16 + l16)*32 + quad*8];
    }
    #pragma unroll
    for (int j = 0; j < 2; ++j) {
      bh[j] = *(const bf16x8*)&Bh[(wc*32 + j*16 + l16)*32 + quad*8];
      bl[j] = *(const bf16x8*)&Bl[(wc*32 + j*16 + l16)*32 + quad*8];
    }
    __syncthreads();
    if (k0 + 32 < EDIM) {
      const short* p;
      p = gAh + k0 + 32;  gl_lds16(p, lAh);  gl_lds16(p + 64*EDIM, lAh + 64*32);
      p = gAl + k0 + 32;  gl_lds16(p, lAl);  gl_lds16(p + 64*EDIM, lAl + 64*32);
      gl_lds16(gBh + k0 + 32, lBh);  gl_lds16(gBl + k0 + 32, lBl);
    }
    #pragma unroll
    for (int i = 0; i < 4; ++i)
      #pragma unroll
      for (int j = 0; j < 2; ++j) {
        acc[i][j] = __builtin_amdgcn_mfma_f32_16x16x32_bf16(ah[i], bh[j], acc[i][j], 0, 0, 0);
        acc[i][j] = __builtin_amdgcn_mfma_f32_16x16x32_bf16(ah[i], bl[j], acc[i][j], 0, 0, 0);
        acc[i][j] = __builtin_amdgcn_mfma_f32_16x16x32_bf16(al[i], bh[j], acc[i][j], 0, 0, 0);
      }
  }
  #pragma unroll
  for (int j = 0; j < 2; ++j) {
    int col = col0 + wc*32 + j*16 + l16;
    float bv = bias[col];
    #pragma unroll
    for (int i = 0; i < 4; ++i) {
      int rowb = row0 + wr*64 + i*16 + quad*4;
      #pragma unroll
      for (int r = 0; r < 4; ++r)
        T1[(size_t)(rowb + r) * HIDDEN + col] = fmaxf(acc[i][j][r] + bv, 0.0f);
    }
  }
}

// ---------------- kernel 2: t1 GEMM + QKV GEMM, interleaved 1:3 ----------------
__global__ __launch_bounds__(256) void mega_gemm1(
    const short* __restrict__ qh, const short* __restrict__ ql,
    const short* __restrict__ w1h, const short* __restrict__ w1l,
    const float* __restrict__ inf1_b, float* __restrict__ T1,
    const short* __restrict__ Wq, const short* __restrict__ Wk,
    const short* __restrict__ Wv,
    const float* __restrict__ qb, const float* __restrict__ kb,
    const float* __restrict__ vb,
    short* __restrict__ Qp, short* __restrict__ Kp, short* __restrict__ Vp)
{
  __shared__ __attribute__((aligned(16))) short smem[12288];   // 24 KB union
  int blk = blockIdx.x;
  if ((blk & 3) == 3) {
    int id = blk >> 2;                         // [0,256)
    gemm_t1_body(smem, qh, ql, w1h, w1l, inf1_b, T1,
                 (id & 31) * 128, (id >> 5) * 64);
  } else {
    int id = (blk >> 2) * 3 + (blk & 3);       // [0,768)
    int row0 = (id & 31) * 128;
    int rest = id >> 5;                        // [0,24)
    int mat = rest >> 3, cb = rest & 7;
    const short* B   = (mat == 0) ? Wq : (mat == 1) ? Wk : Wv;
    const float* bia = (mat == 0) ? qb : (mat == 1) ? kb : vb;
    short* out       = (mat == 0) ? Qp : (mat == 1) ? Kp : Vp;
    // q scale folds D^-0.5 * log2(e) (flash softmax runs in exp2 domain)
    float scale      = (mat == 0) ? 0.18033688011112042f : 1.0f;
    gemm128_body<false>(smem, qh, B, bia, (void*)out, row0, cb * 128, scale);
  }
}

// ---------------- kernel 3: head-mask + V-transpose in one launch ----------------
__global__ __launch_bounds__(256) void mid_kernel(
    const float* __restrict__ T1, const float* __restrict__ inf2_w,
    const float* __restrict__ inf2_b, const float* __restrict__ head_sig,
    float* __restrict__ maskbuf,
    const short* __restrict__ Vp, short* __restrict__ VT)
{
  __shared__ __attribute__((aligned(16))) float fsm[16*HIDDEN + 16*SIGD + 16*NHEAD];
  int blk = blockIdx.x;
  const int tid = threadIdx.x;
  if (blk < 256) {
    // ---- head mask: t2 = t1 @ inf2_w^T + b ; s = t2 @ head_sig^T ; top-12 ----
    float (*t1s)[HIDDEN] = (float(*)[HIDDEN])fsm;
    float (*t2s)[SIGD]   = (float(*)[SIGD])(fsm + 16*HIDDEN);
    float (*ss)[NHEAD]   = (float(*)[NHEAD])(fsm + 16*HIDDEN + 16*SIGD);
    const int tok0 = blk * 16;
    {
      int row = tid >> 4, c0 = (tid & 15) * 32;
      const float* src = T1 + (size_t)(tok0 + row) * HIDDEN + c0;
      #pragma unroll
      for (int u = 0; u < 8; ++u)
        *(float4*)&t1s[row][c0 + u*4] = *(const float4*)(src + u*4);
    }
    __syncthreads();
    #pragma unroll
    for (int it = 0; it < 4; ++it) {
      int idx = tid + it * 256;
      int tok = idx >> 6, j = idx & 63;
      const float4* w4 = (const float4*)(inf2_w + (size_t)j * HIDDEN);
      const float4* t4 = (const float4*)(&t1s[tok][0]);
      float a = inf2_b[j];
      for (int k = 0; k < HIDDEN/4; ++k) {
        float4 wv = w4[k], tv = t4[k];
        a += tv.x*wv.x + tv.y*wv.y + tv.z*wv.z + tv.w*wv.w;
      }
      t2s[tok][j] = a;
    }
    __syncthreads();
    {
      int tok = tid >> 4, h = tid & 15;
      float a = 0.f;
      for (int d = 0; d < SIGD; ++d) a += t2s[tok][d] * head_sig[h*SIGD + d];
      ss[tok][h] = a;
    }
    __syncthreads();
    {
      int tok = tid >> 4, h = tid & 15;
      float sv = ss[tok][h];
      int cnt = 0;
      #pragma unroll
      for (int j = 0; j < NHEAD; ++j) cnt += (ss[tok][j] > sv) ? 1 : 0;
      int gt = tok0 + tok;
      int s = gt >> 1, b = gt & 1;             // token row = s*B + b
      maskbuf[((size_t)(b*NHEAD + h)) * S_LEN + s] = (cnt < KEEP) ? 1.0f : 0.0f;
    }
  } else {
    // ---- V transpose: Vp (token-major) -> VT[(b*16+h)*64+d][S_LEN] ----
    short (*tile)[72] = (short(*)[72])fsm;
    int t = blk - 256;                          // [0,1024)
    const int s0 = (t & 31) * 64, e0 = ((t >> 5) & 15) * 64, b = t >> 9;
    {
      int sr = tid >> 2, ec = (tid & 3) * 16;
      const short* src = Vp + (size_t)(s0 + sr) * 2048 + b * 1024 + e0 + ec;
      *(uint4*)&tile[sr][ec]     = *(const uint4*)src;
      *(uint4*)&tile[sr][ec + 8] = *(const uint4*)(src + 8);
    }
    __syncthreads();
    {
      int er = tid >> 2, sc = (tid & 3) * 16;
      unsigned pack[8];
      #pragma unroll
      for (int u = 0; u < 8; ++u) {
        unsigned lo = (unsigned short)tile[sc + 2*u][er];
        unsigned hi = (unsigned short)tile[sc + 2*u + 1][er];
        pack[u] = lo | (hi << 16);
      }
      short* dst = VT + (size_t)(b * 1024 + e0 + er) * 2048 + s0 + sc;
      *(uint4*)(dst)     = *(uint4*)&pack[0];
      *(uint4*)(dst + 8) = *(uint4*)&pack[4];
    }
  }
}

// ---------------- kernel 4: flash attention (exp2 domain) ----------------
// v4 = R0 structure EXACTLY (KV=128, direct load->store staging between the
// two barriers, full softmax, no prefetch regs, no defer-max) with ONE change:
// all LDS layouts moved to the 68-short-stride family (word-stride 34 = 2 mod
// 32) that measured ZERO bank conflicts in R1/R2. 128-wide buffers split into
// two 64-col banks. + setprio around MFMA clusters.
// LDS = 3 x 17408 = 52224 B -> 3 blocks/CU.
__global__ __launch_bounds__(256) void flash_attn(
    short* QpOg, const short* __restrict__ Kp, const short* __restrict__ VT,
    const float* __restrict__ maskbuf)
{
  __shared__ __attribute__((aligned(16))) short Ks[128][68];    // 17408 B
  __shared__ __attribute__((aligned(16))) short Vt[2][64][68];  // 17408 B (rows=d, two 64-kv banks)
  __shared__ __attribute__((aligned(16))) short uni[8704];      // Qstage 64x68 | Ps[w][2][16][68]
  const int bh = blockIdx.x;
  const int b = bh >> 4, h = bh & 15;
  const int q0 = blockIdx.y * 64;
  const int tid = threadIdx.x;
  const int wave = tid >> 6, lane = tid & 63;
  const int quad = lane >> 4, l16 = lane & 15;
  const size_t colbase = (size_t)b * EDIM + h * DHEAD;
  const size_t rstride = (size_t)BATCH * EDIM;   // 2048

  const int r4 = tid >> 2, c16 = (tid & 3) * 16;
  const short* gK = Kp + (size_t)r4 * rstride + colbase + c16;   // +kv0*rstride per tile
  const short* gV = VT + (size_t)(bh * 64 + r4) * S_LEN + c16;   // +kv0 per tile

  {  // stage Q into uni, read fragments to regs
    const short* src = QpOg + (size_t)(q0 + r4) * rstride + colbase + c16;
    *(uint4*)&uni[r4*68 + c16]     = *(const uint4*)src;
    *(uint4*)&uni[r4*68 + c16 + 8] = *(const uint4*)(src + 8);
  }
  __syncthreads();
  bf16x8 aq0 = *(const bf16x8*)&uni[(wave*16 + l16)*68 + quad*8];
  bf16x8 aq1 = *(const bf16x8*)&uni[(wave*16 + l16)*68 + 32 + quad*8];
  short* Psw = &uni[wave * 2176];        // per-wave [2 halves][16 rows][68]

  float m_i[4], l_i[4];
  f32x4 oacc[4];
  #pragma unroll
  for (int r = 0; r < 4; ++r) { m_i[r] = -1e30f; l_i[r] = 0.f; }
  #pragma unroll
  for (int dt = 0; dt < 4; ++dt) oacc[dt] = f32x4{0.f, 0.f, 0.f, 0.f};

  for (int kv0 = 0; kv0 < S_LEN; kv0 += 128) {
    __syncthreads();              // prev tile's LDS reads complete
    {  // stage K (two 64-row halves) and V^T (two 64-kv banks), direct ld->st
      const short* nK = gK + (size_t)kv0 * rstride;
      const short* nV = gV + kv0;
      uint4 ka0 = *(const uint4*)nK;
      uint4 ka1 = *(const uint4*)(nK + 8);
      uint4 kb0 = *(const uint4*)(nK + 64*rstride);
      uint4 kb1 = *(const uint4*)(nK + 64*rstride + 8);
      uint4 va0 = *(const uint4*)nV;
      uint4 va1 = *(const uint4*)(nV + 8);
      uint4 vb0 = *(const uint4*)(nV + 64);
      uint4 vb1 = *(const uint4*)(nV + 72);
      *(uint4*)&Ks[r4][c16]        = ka0;
      *(uint4*)&Ks[r4][c16 + 8]    = ka1;
      *(uint4*)&Ks[r4+64][c16]     = kb0;
      *(uint4*)&Ks[r4+64][c16 + 8] = kb1;
      *(uint4*)&Vt[0][r4][c16]     = va0;
      *(uint4*)&Vt[0][r4][c16 + 8] = va1;
      *(uint4*)&Vt[1][r4][c16]     = vb0;
      *(uint4*)&Vt[1][r4][c16 + 8] = vb1;
    }
    __syncthreads();
    f32x4 sacc[8];
    #pragma unroll
    for (int c = 0; c < 8; ++c) sacc[c] = f32x4{0.f, 0.f, 0.f, 0.f};
    __builtin_amdgcn_s_setprio(1);
    #pragma unroll
    for (int c = 0; c < 8; ++c) {
      bf16x8 b0 = *(const bf16x8*)&Ks[c*16 + l16][quad*8];
      bf16x8 b1 = *(const bf16x8*)&Ks[c*16 + l16][32 + quad*8];
      sacc[c] = __builtin_amdgcn_mfma_f32_16x16x32_bf16(aq0, b0, sacc[c], 0, 0, 0);
      sacc[c] = __builtin_amdgcn_mfma_f32_16x16x32_bf16(aq1, b1, sacc[c], 0, 0, 0);
    }
    __builtin_amdgcn_s_setprio(0);
    #pragma unroll
    for (int r = 0; r < 4; ++r) {
      float vmax = fmaxf(fmaxf(fmaxf(sacc[0][r], sacc[1][r]),
                               fmaxf(sacc[2][r], sacc[3][r])),
                         fmaxf(fmaxf(sacc[4][r], sacc[5][r]),
                               fmaxf(sacc[6][r], sacc[7][r])));
      vmax = row_max16(vmax);
      float mnew = fmaxf(m_i[r], vmax);
      float alpha = fexp2(m_i[r] - mnew);
      float rsum = 0.f;
      short* prow = &Psw[(quad*4 + r)*68 + l16];
      #pragma unroll
      for (int p = 0; p < 4; ++p) {
        float ea = fexp2(sacc[2*p][r]   - mnew);
        float eb = fexp2(sacc[2*p+1][r] - mnew);
        unsigned pk = __builtin_amdgcn_perm(
            __builtin_bit_cast(unsigned, eb),
            __builtin_bit_cast(unsigned, ea), 0x07060302u);
        short* pr = prow + (p >> 1) * 1088;          // kv-half bank
        pr[(2*(p & 1))*16]     = (short)(pk & 0xffffu);
        pr[(2*(p & 1) + 1)*16] = (short)(pk >> 16);
        rsum += ea + eb;
      }
      rsum = row_sum16(rsum);
      l_i[r] = l_i[r] * alpha + rsum;
      m_i[r] = mnew;
      #pragma unroll
      for (int dt = 0; dt < 4; ++dt) oacc[dt][r] *= alpha;
    }
    asm volatile("s_waitcnt lgkmcnt(0)" ::: "memory");   // Ps visible (same wave)
    __builtin_amdgcn_s_setprio(1);
    #pragma unroll
    for (int ks = 0; ks < 4; ++ks) {
      bf16x8 ap = *(const bf16x8*)&Psw[(ks>>1)*1088 + l16*68 + (ks&1)*32 + quad*8];
      #pragma unroll
      for (int dt = 0; dt < 4; ++dt) {
        bf16x8 bb = *(const bf16x8*)&Vt[ks>>1][dt*16 + l16][(ks&1)*32 + quad*8];
        oacc[dt] = __builtin_amdgcn_mfma_f32_16x16x32_bf16(ap, bb, oacc[dt], 0, 0, 0);
      }
    }
    __builtin_amdgcn_s_setprio(0);
  }
  #pragma unroll
  for (int r = 0; r < 4; ++r) {
    int s = q0 + wave*16 + quad*4 + r;
    float mk = maskbuf[((size_t)(b*NHEAD + h)) * S_LEN + s];
    float scale = mk / l_i[r];
    short* dst = QpOg + (size_t)s * rstride + colbase;
    #pragma unroll
    for (int dt = 0; dt < 4; ++dt)
      dst[dt*16 + l16] = f2bf(oacc[dt][r] * scale);
  }
}

// ---------------- kernel 5: out projection ----------------
__global__ __launch_bounds__(256) void gemm_out(
    const short* __restrict__ A, const short* __restrict__ W,
    const float* __restrict__ bias, float* __restrict__ out)
{
  __shared__ __attribute__((aligned(16))) short smem[8192];
  gemm128_body<true>(smem, A, W, bias, (void*)out,
                     blockIdx.x * 128, blockIdx.y * 128, 1.0f);
}

extern "C" void kernel_launch(void* const* d_in, const int* in_sizes, int n_in,
                              void* d_out, int out_size, void* d_ws, size_t ws_size,
                              hipStream_t stream)
{
  const float* query   = (const float*)d_in[0];
  const float* q_w     = (const float*)d_in[1];
  const float* q_b     = (const float*)d_in[2];
  const float* k_w     = (const float*)d_in[3];
  const float* k_b     = (const float*)d_in[4];
  const float* v_w     = (const float*)d_in[5];
  const float* v_b     = (const float*)d_in[6];
  const float* out_w   = (const float*)d_in[7];
  const float* out_b   = (const float*)d_in[8];
  const float* inf1_w  = (const float*)d_in[9];
  const float* inf1_b  = (const float*)d_in[10];
  const float* inf2_w  = (const float*)d_in[11];
  const float* inf2_b  = (const float*)d_in[12];
  const float* head_sig= (const float*)d_in[13];

  char* ws = (char*)d_ws;
  short* qh      = (short*)(ws);
  short* VTb     = (short*)(ws);
  short* ql      = (short*)(ws + (size_t)( 8u<<20));
  float* maskbuf = (float*)(ws + (size_t)( 8u<<20));
  short* Qp      = (short*)(ws + (size_t)(16u<<20));
  short* Kp      = (short*)(ws + (size_t)(24u<<20));
  short* Vp      = (short*)(ws + (size_t)(32u<<20));
  short* Wo      = (short*)(ws + (size_t)(40u<<20));
  char* ob = (char*)d_out;
  float* T1  = (float*)(ob);
  short* w1h = (short*)(ob + (size_t)( 8u<<20));
  short* w1l = (short*)(ob + (size_t)( 9u<<20));
  short* Wq  = (short*)(ob + (size_t)(10u<<20));
  short* Wk  = (short*)(ob + (size_t)(12u<<20));
  short* Wv  = (short*)(ob + (size_t)(14u<<20));
  float* out = (float*)d_out;

  dim3 blk(256);
  cvt_all<<<dim3(8704), blk, 0, stream>>>(query, inf1_w, q_w, k_w, v_w, out_w,
                                          qh, ql, w1h, w1l, Wq, Wk, Wv, Wo);
  mega_gemm1<<<dim3(1024), blk, 0, stream>>>(qh, ql, w1h, w1l, inf1_b, T1,
                                             Wq, Wk, Wv, q_b, k_b, v_b, Qp, Kp, Vp);
  mid_kernel<<<dim3(1280), blk, 0, stream>>>(T1, inf2_w, inf2_b, head_sig, maskbuf,
                                             Vp, VTb);
  flash_attn<<<dim3(32, 32), blk, 0, stream>>>(Qp, Kp, VTb, maskbuf);
  gemm_out<<<dim3(32, 8), blk, 0, stream>>>(Qp, Wo, out_b, out);
}

// Round 4
// 320.834 us; speedup vs baseline: 1.1253x; 1.1036x over previous
//
#include <hip/hip_runtime.h>
#include <hip/hip_bf16.h>

#define S_LEN 2048
#define BATCH 2
#define EDIM 1024
#define NHEAD 16
#define DHEAD 64
#define HIDDEN 512
#define SIGD 64
#define KEEP 12           // NUM_HEADS - INACTIVE

typedef __attribute__((ext_vector_type(8))) short bf16x8;
typedef __attribute__((ext_vector_type(4))) float f32x4;

static __device__ __forceinline__ float bf2f(short s) {
  unsigned int u = ((unsigned int)(unsigned short)s) << 16;
  float f; __builtin_memcpy(&f, &u, 4); return f;
}
static __device__ __forceinline__ short f2bf(float f) {
  unsigned int u; __builtin_memcpy(&u, &f, 4);
  u += 0x7fffu + ((u >> 16) & 1u);   // round-to-nearest-even
  return (short)(u >> 16);
}

#if __has_builtin(__builtin_amdgcn_exp2f)
static __device__ __forceinline__ float fexp2(float x) { return __builtin_amdgcn_exp2f(x); }
#else
static __device__ __forceinline__ float fexp2(float x) { return exp2f(x); }
#endif

// async global->LDS, 16B per lane. LDS dest is wave-uniform base + lane*16.
static __device__ __forceinline__ void gl_lds16(const short* g, short* l) {
  __builtin_amdgcn_global_load_lds(
      (const __attribute__((address_space(1))) unsigned int*)g,
      (__attribute__((address_space(3))) unsigned int*)l, 16, 0, 0);
}

// DPP all-reduce across the 16 lanes of a DPP row (= our quad group).
template<int CTRL>
static __device__ __forceinline__ float dpp_movf(float x) {
  return __builtin_bit_cast(float, __builtin_amdgcn_update_dpp(
      0, __builtin_bit_cast(int, x), CTRL, 0xF, 0xF, true));
}
static __device__ __forceinline__ float row_max16(float v) {
  v = fmaxf(v, dpp_movf<0x128>(v));   // row_ror:8
  v = fmaxf(v, dpp_movf<0x124>(v));   // row_ror:4
  v = fmaxf(v, dpp_movf<0x122>(v));   // row_ror:2
  v = fmaxf(v, dpp_movf<0x121>(v));   // row_ror:1
  return v;
}
static __device__ __forceinline__ float row_sum16(float v) {
  v += dpp_movf<0x128>(v);
  v += dpp_movf<0x124>(v);
  v += dpp_movf<0x122>(v);
  v += dpp_movf<0x121>(v);
  return v;
}

// ---------------- kernel 1: ALL dtype conversions in one launch ----------------
// [0,4096): query hi/lo split. [4096,4608): inf1_w hi/lo split.
// [4608,5632) Wq, [5632,6656) Wk, [6656,7680) Wv, [7680,8704) Wo (plain bf16).
__global__ __launch_bounds__(256) void cvt_all(
    const float* __restrict__ query, const float* __restrict__ inf1_w,
    const float* __restrict__ qw, const float* __restrict__ kw,
    const float* __restrict__ vw, const float* __restrict__ ow,
    short* __restrict__ qh, short* __restrict__ ql,
    short* __restrict__ w1h, short* __restrict__ w1l,
    short* __restrict__ Wq, short* __restrict__ Wk,
    short* __restrict__ Wv, short* __restrict__ Wo)
{
  int blk = blockIdx.x;
  if (blk < 4608) {              // split sections
    const float* in; short *oh, *ol; int i;
    if (blk < 4096) { in = query;  oh = qh;  ol = ql;  i = (blk * 256 + threadIdx.x) * 4; }
    else            { in = inf1_w; oh = w1h; ol = w1l; i = ((blk - 4096) * 256 + threadIdx.x) * 4; }
    float4 f = *(const float4*)(in + i);
    union { short s[4]; uint2 v; } uh, ul;
    float x[4] = {f.x, f.y, f.z, f.w};
    #pragma unroll
    for (int u = 0; u < 4; ++u) {
      short h = f2bf(x[u]);
      uh.s[u] = h;
      ul.s[u] = f2bf(x[u] - bf2f(h));
    }
    *(uint2*)(oh + i) = uh.v;
    *(uint2*)(ol + i) = ul.v;
  } else {                       // plain bf16 sections (1024 blocks each)
    int t = blk - 4608;
    int mat = t >> 10, sub = t & 1023;
    const float* in = (mat == 0) ? qw : (mat == 1) ? kw : (mat == 2) ? vw : ow;
    short* out      = (mat == 0) ? Wq : (mat == 1) ? Wk : (mat == 2) ? Wv : Wo;
    int i = (sub * 256 + threadIdx.x) * 4;
    float4 f = *(const float4*)(in + i);
    union { short s[4]; uint2 v; } u;
    u.s[0] = f2bf(f.x); u.s[1] = f2bf(f.y); u.s[2] = f2bf(f.z); u.s[3] = f2bf(f.w);
    *(uint2*)(out + i) = u.v;
  }
}

// ---------------- m97-style 128x128 GEMM body (smem passed in) ----------------
template<bool F32OUT>
static __device__ __forceinline__ void gemm128_body(
    short* smem,
    const short* __restrict__ A, const short* __restrict__ B,
    const float* __restrict__ bias, void* __restrict__ outv,
    int row0, int col0, float scale)
{
  short* As = smem;              // 128*32
  short* Bs = smem + 128*32;     // 128*32
  const int tid  = threadIdx.x;
  const int wave = tid >> 6, lane = tid & 63;
  const int quad = lane >> 4, l16 = lane & 15;
  const int wr = wave >> 1, wc = wave & 1;
  const int lr = lane >> 2, lc8 = (lane & 3) * 8;

  const short* gA = A + (size_t)(row0 + wave*16 + lr) * EDIM + lc8;
  const short* gB = B + (size_t)(col0 + wave*16 + lr) * EDIM + lc8;
  short* lA = As + wave*512;
  short* lB = Bs + wave*512;

  f32x4 acc[4][4] = {};
  gl_lds16(gA, lA);  gl_lds16(gA + 64*EDIM, lA + 64*32);
  gl_lds16(gB, lB);  gl_lds16(gB + 64*EDIM, lB + 64*32);

  for (int k0 = 0; k0 < EDIM; k0 += 32) {
    __syncthreads();
    bf16x8 af[4], bfr[4];
    #pragma unroll
    for (int i = 0; i < 4; ++i)
      af[i] = *(const bf16x8*)&As[(wr*64 + i*16 + l16)*32 + quad*8];
    #pragma unroll
    for (int j = 0; j < 4; ++j)
      bfr[j] = *(const bf16x8*)&Bs[(wc*64 + j*16 + l16)*32 + quad*8];
    __syncthreads();
    if (k0 + 32 < EDIM) {
      const short* gA2 = gA + k0 + 32;
      const short* gB2 = gB + k0 + 32;
      gl_lds16(gA2, lA);  gl_lds16(gA2 + 64*EDIM, lA + 64*32);
      gl_lds16(gB2, lB);  gl_lds16(gB2 + 64*EDIM, lB + 64*32);
    }
    #pragma unroll
    for (int i = 0; i < 4; ++i)
      #pragma unroll
      for (int j = 0; j < 4; ++j)
        acc[i][j] = __builtin_amdgcn_mfma_f32_16x16x32_bf16(af[i], bfr[j], acc[i][j], 0, 0, 0);
  }
  #pragma unroll
  for (int j = 0; j < 4; ++j) {
    int col = col0 + wc*64 + j*16 + l16;
    float bv = bias[col];
    #pragma unroll
    for (int i = 0; i < 4; ++i) {
      int rowb = row0 + wr*64 + i*16 + quad*4;
      #pragma unroll
      for (int r = 0; r < 4; ++r) {
        float v = (acc[i][j][r] + bv) * scale;
        if constexpr (F32OUT) {
          ((float*)outv)[(size_t)(rowb + r) * EDIM + col] = v;
        } else {
          ((short*)outv)[(size_t)(rowb + r) * EDIM + col] = f2bf(v);
        }
      }
    }
  }
}

// t1 body: 128x64 tile, hi/lo-split (3 MFMAs, fp32-accurate), relu -> T1 fp32.
static __device__ __forceinline__ void gemm_t1_body(
    short* smem,
    const short* __restrict__ Agh, const short* __restrict__ Agl,
    const short* __restrict__ Bgh, const short* __restrict__ Bgl,
    const float* __restrict__ bias, float* __restrict__ T1,
    int row0, int col0)
{
  short* Ah = smem;              // 128*32
  short* Al = smem + 4096;      // 128*32
  short* Bh = smem + 8192;      // 64*32
  short* Bl = smem + 10240;     // 64*32
  const int tid  = threadIdx.x;
  const int wave = tid >> 6, lane = tid & 63;
  const int quad = lane >> 4, l16 = lane & 15;
  const int wr = wave >> 1, wc = wave & 1;
  const int lr = lane >> 2, lc8 = (lane & 3) * 8;

  const short* gAh = Agh + (size_t)(row0 + wave*16 + lr) * EDIM + lc8;
  const short* gAl = Agl + (size_t)(row0 + wave*16 + lr) * EDIM + lc8;
  const short* gBh = Bgh + (size_t)(col0 + wave*16 + lr) * EDIM + lc8;
  const short* gBl = Bgl + (size_t)(col0 + wave*16 + lr) * EDIM + lc8;
  short* lAh = Ah + wave*512;  short* lAl = Al + wave*512;
  short* lBh = Bh + wave*512;  short* lBl = Bl + wave*512;

  f32x4 acc[4][2] = {};
  gl_lds16(gAh, lAh);  gl_lds16(gAh + 64*EDIM, lAh + 64*32);
  gl_lds16(gAl, lAl);  gl_lds16(gAl + 64*EDIM, lAl + 64*32);
  gl_lds16(gBh, lBh);  gl_lds16(gBl, lBl);

  for (int k0 = 0; k0 < EDIM; k0 += 32) {
    __syncthreads();
    bf16x8 ah[4], al[4], bh[2], bl[2];
    #pragma unroll
    for (int i = 0; i < 4; ++i) {
      ah[i] = *(const bf16x8*)&Ah[(wr*64 + i*16 + l16)*32 + quad*8];
      al[i] = *(const bf16x8*)&Al[(wr*64 + i*16 + l16)*32 + quad*8];
    }
    #pragma unroll
    for (int j = 0; j < 2; ++j) {
      bh[j] = *(const bf16x8*)&Bh[(wc*32 + j*16 + l16)*32 + quad*8];
      bl[j] = *(const bf16x8*)&Bl[(wc*32 + j*16 + l16)*32 + quad*8];
    }
    __syncthreads();
    if (k0 + 32 < EDIM) {
      const short* p;
      p = gAh + k0 + 32;  gl_lds16(p, lAh);  gl_lds16(p + 64*EDIM, lAh + 64*32);
      p = gAl + k0 + 32;  gl_lds16(p, lAl);  gl_lds16(p + 64*EDIM, lAl + 64*32);
      gl_lds16(gBh + k0 + 32, lBh);  gl_lds16(gBl + k0 + 32, lBl);
    }
    #pragma unroll
    for (int i = 0; i < 4; ++i)
      #pragma unroll
      for (int j = 0; j < 2; ++j) {
        acc[i][j] = __builtin_amdgcn_mfma_f32_16x16x32_bf16(ah[i], bh[j], acc[i][j], 0, 0, 0);
        acc[i][j] = __builtin_amdgcn_mfma_f32_16x16x32_bf16(ah[i], bl[j], acc[i][j], 0, 0, 0);
        acc[i][j] = __builtin_amdgcn_mfma_f32_16x16x32_bf16(al[i], bh[j], acc[i][j], 0, 0, 0);
      }
  }
  #pragma unroll
  for (int j = 0; j < 2; ++j) {
    int col = col0 + wc*32 + j*16 + l16;
    float bv = bias[col];
    #pragma unroll
    for (int i = 0; i < 4; ++i) {
      int rowb = row0 + wr*64 + i*16 + quad*4;
      #pragma unroll
      for (int r = 0; r < 4; ++r)
        T1[(size_t)(rowb + r) * HIDDEN + col] = fmaxf(acc[i][j][r] + bv, 0.0f);
    }
  }
}

// ---------------- kernel 2: t1 GEMM + QKV GEMM, interleaved 1:3 ----------------
__global__ __launch_bounds__(256) void mega_gemm1(
    const short* __restrict__ qh, const short* __restrict__ ql,
    const short* __restrict__ w1h, const short* __restrict__ w1l,
    const float* __restrict__ inf1_b, float* __restrict__ T1,
    const short* __restrict__ Wq, const short* __restrict__ Wk,
    const short* __restrict__ Wv,
    const float* __restrict__ qb, const float* __restrict__ kb,
    const float* __restrict__ vb,
    short* __restrict__ Qp, short* __restrict__ Kp, short* __restrict__ Vp)
{
  __shared__ __attribute__((aligned(16))) short smem[12288];   // 24 KB union
  int blk = blockIdx.x;
  if ((blk & 3) == 3) {
    int id = blk >> 2;                         // [0,256)
    gemm_t1_body(smem, qh, ql, w1h, w1l, inf1_b, T1,
                 (id & 31) * 128, (id >> 5) * 64);
  } else {
    int id = (blk >> 2) * 3 + (blk & 3);       // [0,768)
    int row0 = (id & 31) * 128;
    int rest = id >> 5;                        // [0,24)
    int mat = rest >> 3, cb = rest & 7;
    const short* B   = (mat == 0) ? Wq : (mat == 1) ? Wk : Wv;
    const float* bia = (mat == 0) ? qb : (mat == 1) ? kb : vb;
    short* out       = (mat == 0) ? Qp : (mat == 1) ? Kp : Vp;
    // q scale folds D^-0.5 * log2(e) (flash softmax runs in exp2 domain)
    float scale      = (mat == 0) ? 0.18033688011112042f : 1.0f;
    gemm128_body<false>(smem, qh, B, bia, (void*)out, row0, cb * 128, scale);
  }
}

// ---------------- kernel 3: head-mask + V-transpose in one launch ----------------
__global__ __launch_bounds__(256) void mid_kernel(
    const float* __restrict__ T1, const float* __restrict__ inf2_w,
    const float* __restrict__ inf2_b, const float* __restrict__ head_sig,
    float* __restrict__ maskbuf,
    const short* __restrict__ Vp, short* __restrict__ VT)
{
  __shared__ __attribute__((aligned(16))) float fsm[16*HIDDEN + 16*SIGD + 16*NHEAD];
  int blk = blockIdx.x;
  const int tid = threadIdx.x;
  if (blk < 256) {
    // ---- head mask: t2 = t1 @ inf2_w^T + b ; s = t2 @ head_sig^T ; top-12 ----
    float (*t1s)[HIDDEN] = (float(*)[HIDDEN])fsm;
    float (*t2s)[SIGD]   = (float(*)[SIGD])(fsm + 16*HIDDEN);
    float (*ss)[NHEAD]   = (float(*)[NHEAD])(fsm + 16*HIDDEN + 16*SIGD);
    const int tok0 = blk * 16;
    {
      int row = tid >> 4, c0 = (tid & 15) * 32;
      const float* src = T1 + (size_t)(tok0 + row) * HIDDEN + c0;
      #pragma unroll
      for (int u = 0; u < 8; ++u)
        *(float4*)&t1s[row][c0 + u*4] = *(const float4*)(src + u*4);
    }
    __syncthreads();
    #pragma unroll
    for (int it = 0; it < 4; ++it) {
      int idx = tid + it * 256;
      int tok = idx >> 6, j = idx & 63;
      const float4* w4 = (const float4*)(inf2_w + (size_t)j * HIDDEN);
      const float4* t4 = (const float4*)(&t1s[tok][0]);
      float a = inf2_b[j];
      for (int k = 0; k < HIDDEN/4; ++k) {
        float4 wv = w4[k], tv = t4[k];
        a += tv.x*wv.x + tv.y*wv.y + tv.z*wv.z + tv.w*wv.w;
      }
      t2s[tok][j] = a;
    }
    __syncthreads();
    {
      int tok = tid >> 4, h = tid & 15;
      float a = 0.f;
      for (int d = 0; d < SIGD; ++d) a += t2s[tok][d] * head_sig[h*SIGD + d];
      ss[tok][h] = a;
    }
    __syncthreads();
    {
      int tok = tid >> 4, h = tid & 15;
      float sv = ss[tok][h];
      int cnt = 0;
      #pragma unroll
      for (int j = 0; j < NHEAD; ++j) cnt += (ss[tok][j] > sv) ? 1 : 0;
      int gt = tok0 + tok;
      int s = gt >> 1, b = gt & 1;             // token row = s*B + b
      maskbuf[((size_t)(b*NHEAD + h)) * S_LEN + s] = (cnt < KEEP) ? 1.0f : 0.0f;
    }
  } else {
    // ---- V transpose: Vp (token-major) -> VT[(b*16+h)*64+d][S_LEN] ----
    short (*tile)[72] = (short(*)[72])fsm;
    int t = blk - 256;                          // [0,1024)
    const int s0 = (t & 31) * 64, e0 = ((t >> 5) & 15) * 64, b = t >> 9;
    {
      int sr = tid >> 2, ec = (tid & 3) * 16;
      const short* src = Vp + (size_t)(s0 + sr) * 2048 + b * 1024 + e0 + ec;
      *(uint4*)&tile[sr][ec]     = *(const uint4*)src;
      *(uint4*)&tile[sr][ec + 8] = *(const uint4*)(src + 8);
    }
    __syncthreads();
    {
      int er = tid >> 2, sc = (tid & 3) * 16;
      unsigned pack[8];
      #pragma unroll
      for (int u = 0; u < 8; ++u) {
        unsigned lo = (unsigned short)tile[sc + 2*u][er];
        unsigned hi = (unsigned short)tile[sc + 2*u + 1][er];
        pack[u] = lo | (hi << 16);
      }
      short* dst = VT + (size_t)(b * 1024 + e0 + er) * 2048 + s0 + sc;
      *(uint4*)(dst)     = *(uint4*)&pack[0];
      *(uint4*)(dst + 8) = *(uint4*)&pack[4];
    }
  }
}

// ---------------- kernel 4: flash attention (exp2 domain) ----------------
// v5: LDS-instruction-throughput attack.
//  * 32 q-rows per wave (4 waves = 128 q/block): K/V fragment reads per q HALVED.
//  * global_load_lds staging (zero staging ds_writes), linear LDS dest +
//    inverse-XOR-swizzled GLOBAL source (rule #21; XOR is an involution).
//  * all LDS tiles linear-stride (16B-aligned rows -> true ds_read_b128) with
//    chunk-XOR swizzle: Ks/Vt/Qs: chunk ^= (row&7); Ps: chunk ^= ((row>>1)&7).
//  * LDS = 16K (K) + 16K (V) + 32K (Ps, Q-stage unioned) = 64 KB -> 2 blocks/CU;
//    grid 512 = exactly 2/CU, zero tail.
__global__ __launch_bounds__(256) void flash_attn(
    short* QpOg, const short* __restrict__ Kp, const short* __restrict__ VT,
    const float* __restrict__ maskbuf)
{
  __shared__ __attribute__((aligned(16))) short smem[32768];   // 64 KB exactly
  short* KsL = smem;            // [128 kv][64 d]   linear, chunk^=(row&7)
  short* VtL = smem + 8192;     // [64 d][128 kv]   linear, chunk^=(row&7)
  short* PsB = smem + 16384;    // 4 waves x [2 kvhalf][32 row][64], chunk^=((row>>1)&7)
  short* Qs  = smem + 16384;    // [128 q][64 d] union with Ps (pre-loop only)

  const int bh = blockIdx.x;
  const int b = bh >> 4, h = bh & 15;
  const int q0 = blockIdx.y * 128;
  const int tid = threadIdx.x;
  const int wave = tid >> 6, lane = tid & 63;
  const int quad = lane >> 4, l16 = lane & 15;
  const size_t colbase = (size_t)b * EDIM + h * DHEAD;
  const size_t rstride = (size_t)BATCH * EDIM;   // 2048
  short* Psw = PsB + wave * 4096;

  {  // ---- stage Q (swizzled), once ----
    int row = tid >> 1;
    int cb  = (tid & 1) * 4;
    const short* src = QpOg + (size_t)(q0 + row) * rstride + colbase + cb * 8;
    #pragma unroll
    for (int u = 0; u < 4; ++u) {
      uint4 v = *(const uint4*)(src + u * 8);
      *(uint4*)&Qs[row * 64 + (((cb + u) ^ (row & 7)) * 8)] = v;
    }
  }
  __syncthreads();
  bf16x8 aq[2][2];
  #pragma unroll
  for (int h2 = 0; h2 < 2; ++h2)
    #pragma unroll
    for (int dh = 0; dh < 2; ++dh) {
      int row = wave * 32 + h2 * 16 + l16;       // row&7 == l16&7
      aq[h2][dh] = *(const bf16x8*)&Qs[row * 64 + (((dh * 4 + quad) ^ (l16 & 7)) * 8)];
    }

  // staging lane constants
  const int kxor = (lane & 7) ^ (lane >> 3);      // K: chunk ^ row&7  (row&7 = lane>>3)
  const short* gKbase = Kp + colbase + (size_t)(wave * 32 + (lane >> 3)) * rstride + kxor * 8;
  short* ldsK = KsL + wave * 2048;
  const int vrow_l = lane >> 4;                   // V row low bits within call group
  short* ldsV = VtL + wave * 2048;

  float m_i[2][4], l_i[2][4];
  f32x4 oacc[2][4];
  #pragma unroll
  for (int h2 = 0; h2 < 2; ++h2)
    #pragma unroll
    for (int r = 0; r < 4; ++r) { m_i[h2][r] = -1e30f; l_i[h2][r] = 0.f; }
  #pragma unroll
  for (int h2 = 0; h2 < 2; ++h2)
    #pragma unroll
    for (int dt = 0; dt < 4; ++dt) oacc[h2][dt] = f32x4{0.f, 0.f, 0.f, 0.f};

  for (int kv0 = 0; kv0 < S_LEN; kv0 += 128) {
    __syncthreads();                 // all waves done reading previous tile
    #pragma unroll
    for (int i = 0; i < 4; ++i) {
      // K: rows wave*32 + i*8 + (lane>>3), chunk lane&7 -> linear LDS lane*16
      gl_lds16(gKbase + (size_t)(kv0 + i * 8) * rstride, ldsK + i * 512);
      // V: rows wave*16 + i*4 + (lane>>4), chunk lane&15, swz by row&7
      int vrow = wave * 16 + i * 4 + vrow_l;
      int vx = (lane & 15) ^ ((i & 1) * 4 + vrow_l);
      gl_lds16(VT + (size_t)(bh * 64 + vrow) * S_LEN + kv0 + vx * 8, ldsV + i * 512);
    }
    asm volatile("s_waitcnt vmcnt(0)" ::: "memory");
    __syncthreads();                 // staged tile visible to all waves

    // ---- QK^T: 32 q-rows x 128 kv per wave ----
    f32x4 sacc[2][8];
    #pragma unroll
    for (int h2 = 0; h2 < 2; ++h2)
      #pragma unroll
      for (int c = 0; c < 8; ++c) sacc[h2][c] = f32x4{0.f, 0.f, 0.f, 0.f};
    #pragma unroll
    for (int c = 0; c < 8; ++c) {
      const short* kr = &KsL[(c * 16 + l16) * 64];          // row&7 == l16&7
      bf16x8 b0 = *(const bf16x8*)&kr[((quad     ^ (l16 & 7)) * 8)];
      bf16x8 b1 = *(const bf16x8*)&kr[(((4 + quad) ^ (l16 & 7)) * 8)];
      #pragma unroll
      for (int h2 = 0; h2 < 2; ++h2) {
        sacc[h2][c] = __builtin_amdgcn_mfma_f32_16x16x32_bf16(aq[h2][0], b0, sacc[h2][c], 0, 0, 0);
        sacc[h2][c] = __builtin_amdgcn_mfma_f32_16x16x32_bf16(aq[h2][1], b1, sacc[h2][c], 0, 0, 0);
      }
    }

    // ---- online softmax (exp2 domain), write P to swizzled Ps ----
    #pragma unroll
    for (int h2 = 0; h2 < 2; ++h2) {
      #pragma unroll
      for (int r = 0; r < 4; ++r) {
        float vmax = fmaxf(fmaxf(fmaxf(sacc[h2][0][r], sacc[h2][1][r]),
                                 fmaxf(sacc[h2][2][r], sacc[h2][3][r])),
                           fmaxf(fmaxf(sacc[h2][4][r], sacc[h2][5][r]),
                                 fmaxf(sacc[h2][6][r], sacc[h2][7][r])));
        vmax = row_max16(vmax);
        float mnew = fmaxf(m_i[h2][r], vmax);
        float alpha = fexp2(m_i[h2][r] - mnew);
        float rsum = 0.f;
        int row = h2 * 16 + quad * 4 + r;
        int sw = quad * 2 + (r >> 1);            // (row>>1)&7
        #pragma unroll
        for (int p = 0; p < 4; ++p) {
          float ea = fexp2(sacc[h2][2*p][r]   - mnew);
          float eb = fexp2(sacc[h2][2*p+1][r] - mnew);
          unsigned pk = __builtin_amdgcn_perm(
              __builtin_bit_cast(unsigned, eb),
              __builtin_bit_cast(unsigned, ea), 0x07060302u);
          short* pb = Psw + (p >> 1) * 2048 + row * 64;
          int c1 = ((2*p) & 3) * 2 + (l16 >> 3);       // j1>>3
          int c2 = ((2*p+1) & 3) * 2 + (l16 >> 3);     // j2>>3
          pb[((c1 ^ sw) * 8) + (l16 & 7)] = (short)(pk & 0xffffu);
          pb[((c2 ^ sw) * 8) + (l16 & 7)] = (short)(pk >> 16);
          rsum += ea + eb;
        }
        rsum = row_sum16(rsum);
        l_i[h2][r] = l_i[h2][r] * alpha + rsum;
        m_i[h2][r] = mnew;
        #pragma unroll
        for (int dt = 0; dt < 4; ++dt) oacc[h2][dt][r] *= alpha;
      }
    }
    asm volatile("s_waitcnt lgkmcnt(0)" ::: "memory");   // Ps visible (same wave)

    // ---- PV: V fragments read ONCE, used for both q-halves ----
    #pragma unroll
    for (int ks = 0; ks < 4; ++ks) {
      const short* p0 = Psw + (ks >> 1) * 2048;
      int pc = (((ks & 1) * 4 + quad) ^ (l16 >> 1)) * 8;   // (row>>1)&7 == l16>>1
      bf16x8 ap0 = *(const bf16x8*)&p0[l16 * 64 + pc];
      bf16x8 ap1 = *(const bf16x8*)&p0[(16 + l16) * 64 + pc];
      #pragma unroll
      for (int dt = 0; dt < 4; ++dt) {
        bf16x8 bb = *(const bf16x8*)&VtL[(dt * 16 + l16) * 128 +
                                         (((ks * 4 + quad) ^ (l16 & 7)) * 8)];
        oacc[0][dt] = __builtin_amdgcn_mfma_f32_16x16x32_bf16(ap0, bb, oacc[0][dt], 0, 0, 0);
        oacc[1][dt] = __builtin_amdgcn_mfma_f32_16x16x32_bf16(ap1, bb, oacc[1][dt], 0, 0, 0);
      }
    }
  }

  #pragma unroll
  for (int h2 = 0; h2 < 2; ++h2) {
    #pragma unroll
    for (int r = 0; r < 4; ++r) {
      int s = q0 + wave * 32 + h2 * 16 + quad * 4 + r;
      float mk = maskbuf[((size_t)(b * NHEAD + h)) * S_LEN + s];
      float scale = mk / l_i[h2][r];
      short* dst = QpOg + (size_t)s * rstride + colbase;
      #pragma unroll
      for (int dt = 0; dt < 4; ++dt)
        dst[dt * 16 + l16] = f2bf(oacc[h2][dt][r] * scale);
    }
  }
}

// ---------------- kernel 5: out projection ----------------
__global__ __launch_bounds__(256) void gemm_out(
    const short* __restrict__ A, const short* __restrict__ W,
    const float* __restrict__ bias, float* __restrict__ out)
{
  __shared__ __attribute__((aligned(16))) short smem[8192];
  gemm128_body<true>(smem, A, W, bias, (void*)out,
                     blockIdx.x * 128, blockIdx.y * 128, 1.0f);
}

extern "C" void kernel_launch(void* const* d_in, const int* in_sizes, int n_in,
                              void* d_out, int out_size, void* d_ws, size_t ws_size,
                              hipStream_t stream)
{
  const float* query   = (const float*)d_in[0];
  const float* q_w     = (const float*)d_in[1];
  const float* q_b     = (const float*)d_in[2];
  const float* k_w     = (const float*)d_in[3];
  const float* k_b     = (const float*)d_in[4];
  const float* v_w     = (const float*)d_in[5];
  const float* v_b     = (const float*)d_in[6];
  const float* out_w   = (const float*)d_in[7];
  const float* out_b   = (const float*)d_in[8];
  const float* inf1_w  = (const float*)d_in[9];
  const float* inf1_b  = (const float*)d_in[10];
  const float* inf2_w  = (const float*)d_in[11];
  const float* inf2_b  = (const float*)d_in[12];
  const float* head_sig= (const float*)d_in[13];

  char* ws = (char*)d_ws;
  short* qh      = (short*)(ws);
  short* VTb     = (short*)(ws);
  short* ql      = (short*)(ws + (size_t)( 8u<<20));
  float* maskbuf = (float*)(ws + (size_t)( 8u<<20));
  short* Qp      = (short*)(ws + (size_t)(16u<<20));
  short* Kp      = (short*)(ws + (size_t)(24u<<20));
  short* Vp      = (short*)(ws + (size_t)(32u<<20));
  short* Wo      = (short*)(ws + (size_t)(40u<<20));
  char* ob = (char*)d_out;
  float* T1  = (float*)(ob);
  short* w1h = (short*)(ob + (size_t)( 8u<<20));
  short* w1l = (short*)(ob + (size_t)( 9u<<20));
  short* Wq  = (short*)(ob + (size_t)(10u<<20));
  short* Wk  = (short*)(ob + (size_t)(12u<<20));
  short* Wv  = (short*)(ob + (size_t)(14u<<20));
  float* out = (float*)d_out;

  dim3 blk(256);
  cvt_all<<<dim3(8704), blk, 0, stream>>>(query, inf1_w, q_w, k_w, v_w, out_w,
                                          qh, ql, w1h, w1l, Wq, Wk, Wv, Wo);
  mega_gemm1<<<dim3(1024), blk, 0, stream>>>(qh, ql, w1h, w1l, inf1_b, T1,
                                             Wq, Wk, Wv, q_b, k_b, v_b, Qp, Kp, Vp);
  mid_kernel<<<dim3(1280), blk, 0, stream>>>(T1, inf2_w, inf2_b, head_sig, maskbuf,
                                             Vp, VTb);
  flash_attn<<<dim3(32, 16), blk, 0, stream>>>(Qp, Kp, VTb, maskbuf);
  gemm_out<<<dim3(32, 8), blk, 0, stream>>>(Qp, Wo, out_b, out);
}

// Round 5
// 309.790 us; speedup vs baseline: 1.1654x; 1.0357x over previous
//
#include <hip/hip_runtime.h>
#include <hip/hip_bf16.h>

#define S_LEN 2048
#define BATCH 2
#define EDIM 1024
#define NHEAD 16
#define DHEAD 64
#define HIDDEN 512
#define SIGD 64
#define KEEP 12           // NUM_HEADS - INACTIVE

typedef __attribute__((ext_vector_type(8))) short bf16x8;
typedef __attribute__((ext_vector_type(4))) float f32x4;

static __device__ __forceinline__ float bf2f(short s) {
  unsigned int u = ((unsigned int)(unsigned short)s) << 16;
  float f; __builtin_memcpy(&f, &u, 4); return f;
}
static __device__ __forceinline__ short f2bf(float f) {
  unsigned int u; __builtin_memcpy(&u, &f, 4);
  u += 0x7fffu + ((u >> 16) & 1u);   // round-to-nearest-even
  return (short)(u >> 16);
}

#if __has_builtin(__builtin_amdgcn_exp2f)
static __device__ __forceinline__ float fexp2(float x) { return __builtin_amdgcn_exp2f(x); }
#else
static __device__ __forceinline__ float fexp2(float x) { return exp2f(x); }
#endif

// async global->LDS, 16B per lane. LDS dest is wave-uniform base + lane*16.
static __device__ __forceinline__ void gl_lds16(const short* g, short* l) {
  __builtin_amdgcn_global_load_lds(
      (const __attribute__((address_space(1))) unsigned int*)g,
      (__attribute__((address_space(3))) unsigned int*)l, 16, 0, 0);
}

static __device__ __forceinline__ float bperm_f(int idx, float v) {
  return __builtin_bit_cast(float,
      __builtin_amdgcn_ds_bpermute(idx, __builtin_bit_cast(int, v)));
}

// ---------------- kernel 1: ALL dtype conversions in one launch ----------------
// [0,4096): query hi/lo split. [4096,4608): inf1_w hi/lo split.
// [4608,5632) Wq, [5632,6656) Wk, [6656,7680) Wv, [7680,8704) Wo (plain bf16).
__global__ __launch_bounds__(256) void cvt_all(
    const float* __restrict__ query, const float* __restrict__ inf1_w,
    const float* __restrict__ qw, const float* __restrict__ kw,
    const float* __restrict__ vw, const float* __restrict__ ow,
    short* __restrict__ qh, short* __restrict__ ql,
    short* __restrict__ w1h, short* __restrict__ w1l,
    short* __restrict__ Wq, short* __restrict__ Wk,
    short* __restrict__ Wv, short* __restrict__ Wo)
{
  int blk = blockIdx.x;
  if (blk < 4608) {              // split sections
    const float* in; short *oh, *ol; int i;
    if (blk < 4096) { in = query;  oh = qh;  ol = ql;  i = (blk * 256 + threadIdx.x) * 4; }
    else            { in = inf1_w; oh = w1h; ol = w1l; i = ((blk - 4096) * 256 + threadIdx.x) * 4; }
    float4 f = *(const float4*)(in + i);
    union { short s[4]; uint2 v; } uh, ul;
    float x[4] = {f.x, f.y, f.z, f.w};
    #pragma unroll
    for (int u = 0; u < 4; ++u) {
      short h = f2bf(x[u]);
      uh.s[u] = h;
      ul.s[u] = f2bf(x[u] - bf2f(h));
    }
    *(uint2*)(oh + i) = uh.v;
    *(uint2*)(ol + i) = ul.v;
  } else {                       // plain bf16 sections (1024 blocks each)
    int t = blk - 4608;
    int mat = t >> 10, sub = t & 1023;
    const float* in = (mat == 0) ? qw : (mat == 1) ? kw : (mat == 2) ? vw : ow;
    short* out      = (mat == 0) ? Wq : (mat == 1) ? Wk : (mat == 2) ? Wv : Wo;
    int i = (sub * 256 + threadIdx.x) * 4;
    float4 f = *(const float4*)(in + i);
    union { short s[4]; uint2 v; } u;
    u.s[0] = f2bf(f.x); u.s[1] = f2bf(f.y); u.s[2] = f2bf(f.z); u.s[3] = f2bf(f.w);
    *(uint2*)(out + i) = u.v;
  }
}

// ---------------- m97-style 128x128 GEMM body (smem passed in) ----------------
template<bool F32OUT>
static __device__ __forceinline__ void gemm128_body(
    short* smem,
    const short* __restrict__ A, const short* __restrict__ B,
    const float* __restrict__ bias, void* __restrict__ outv,
    int row0, int col0, float scale)
{
  short* As = smem;              // 128*32
  short* Bs = smem + 128*32;     // 128*32
  const int tid  = threadIdx.x;
  const int wave = tid >> 6, lane = tid & 63;
  const int quad = lane >> 4, l16 = lane & 15;
  const int wr = wave >> 1, wc = wave & 1;
  const int lr = lane >> 2, lc8 = (lane & 3) * 8;

  const short* gA = A + (size_t)(row0 + wave*16 + lr) * EDIM + lc8;
  const short* gB = B + (size_t)(col0 + wave*16 + lr) * EDIM + lc8;
  short* lA = As + wave*512;
  short* lB = Bs + wave*512;

  f32x4 acc[4][4] = {};
  gl_lds16(gA, lA);  gl_lds16(gA + 64*EDIM, lA + 64*32);
  gl_lds16(gB, lB);  gl_lds16(gB + 64*EDIM, lB + 64*32);

  for (int k0 = 0; k0 < EDIM; k0 += 32) {
    __syncthreads();
    bf16x8 af[4], bfr[4];
    #pragma unroll
    for (int i = 0; i < 4; ++i)
      af[i] = *(const bf16x8*)&As[(wr*64 + i*16 + l16)*32 + quad*8];
    #pragma unroll
    for (int j = 0; j < 4; ++j)
      bfr[j] = *(const bf16x8*)&Bs[(wc*64 + j*16 + l16)*32 + quad*8];
    __syncthreads();
    if (k0 + 32 < EDIM) {
      const short* gA2 = gA + k0 + 32;
      const short* gB2 = gB + k0 + 32;
      gl_lds16(gA2, lA);  gl_lds16(gA2 + 64*EDIM, lA + 64*32);
      gl_lds16(gB2, lB);  gl_lds16(gB2 + 64*EDIM, lB + 64*32);
    }
    #pragma unroll
    for (int i = 0; i < 4; ++i)
      #pragma unroll
      for (int j = 0; j < 4; ++j)
        acc[i][j] = __builtin_amdgcn_mfma_f32_16x16x32_bf16(af[i], bfr[j], acc[i][j], 0, 0, 0);
  }
  #pragma unroll
  for (int j = 0; j < 4; ++j) {
    int col = col0 + wc*64 + j*16 + l16;
    float bv = bias[col];
    #pragma unroll
    for (int i = 0; i < 4; ++i) {
      int rowb = row0 + wr*64 + i*16 + quad*4;
      #pragma unroll
      for (int r = 0; r < 4; ++r) {
        float v = (acc[i][j][r] + bv) * scale;
        if constexpr (F32OUT) {
          ((float*)outv)[(size_t)(rowb + r) * EDIM + col] = v;
        } else {
          ((short*)outv)[(size_t)(rowb + r) * EDIM + col] = f2bf(v);
        }
      }
    }
  }
}

// t1 body: 128x64 tile, hi/lo-split (3 MFMAs, fp32-accurate), relu -> T1 fp32.
static __device__ __forceinline__ void gemm_t1_body(
    short* smem,
    const short* __restrict__ Agh, const short* __restrict__ Agl,
    const short* __restrict__ Bgh, const short* __restrict__ Bgl,
    const float* __restrict__ bias, float* __restrict__ T1,
    int row0, int col0)
{
  short* Ah = smem;              // 128*32
  short* Al = smem + 4096;      // 128*32
  short* Bh = smem + 8192;      // 64*32
  short* Bl = smem + 10240;     // 64*32
  const int tid  = threadIdx.x;
  const int wave = tid >> 6, lane = tid & 63;
  const int quad = lane >> 4, l16 = lane & 15;
  const int wr = wave >> 1, wc = wave & 1;
  const int lr = lane >> 2, lc8 = (lane & 3) * 8;

  const short* gAh = Agh + (size_t)(row0 + wave*16 + lr) * EDIM + lc8;
  const short* gAl = Agl + (size_t)(row0 + wave*16 + lr) * EDIM + lc8;
  const short* gBh = Bgh + (size_t)(col0 + wave*16 + lr) * EDIM + lc8;
  const short* gBl = Bgl + (size_t)(col0 + wave*16 + lr) * EDIM + lc8;
  short* lAh = Ah + wave*512;  short* lAl = Al + wave*512;
  short* lBh = Bh + wave*512;  short* lBl = Bl + wave*512;

  f32x4 acc[4][2] = {};
  gl_lds16(gAh, lAh);  gl_lds16(gAh + 64*EDIM, lAh + 64*32);
  gl_lds16(gAl, lAl);  gl_lds16(gAl + 64*EDIM, lAl + 64*32);
  gl_lds16(gBh, lBh);  gl_lds16(gBl, lBl);

  for (int k0 = 0; k0 < EDIM; k0 += 32) {
    __syncthreads();
    bf16x8 ah[4], al[4], bh[2], bl[2];
    #pragma unroll
    for (int i = 0; i < 4; ++i) {
      ah[i] = *(const bf16x8*)&Ah[(wr*64 + i*16 + l16)*32 + quad*8];
      al[i] = *(const bf16x8*)&Al[(wr*64 + i*16 + l16)*32 + quad*8];
    }
    #pragma unroll
    for (int j = 0; j < 2; ++j) {
      bh[j] = *(const bf16x8*)&Bh[(wc*32 + j*16 + l16)*32 + quad*8];
      bl[j] = *(const bf16x8*)&Bl[(wc*32 + j*16 + l16)*32 + quad*8];
    }
    __syncthreads();
    if (k0 + 32 < EDIM) {
      const short* p;
      p = gAh + k0 + 32;  gl_lds16(p, lAh);  gl_lds16(p + 64*EDIM, lAh + 64*32);
      p = gAl + k0 + 32;  gl_lds16(p, lAl);  gl_lds16(p + 64*EDIM, lAl + 64*32);
      gl_lds16(gBh + k0 + 32, lBh);  gl_lds16(gBl + k0 + 32, lBl);
    }
    #pragma unroll
    for (int i = 0; i < 4; ++i)
      #pragma unroll
      for (int j = 0; j < 2; ++j) {
        acc[i][j] = __builtin_amdgcn_mfma_f32_16x16x32_bf16(ah[i], bh[j], acc[i][j], 0, 0, 0);
        acc[i][j] = __builtin_amdgcn_mfma_f32_16x16x32_bf16(ah[i], bl[j], acc[i][j], 0, 0, 0);
        acc[i][j] = __builtin_amdgcn_mfma_f32_16x16x32_bf16(al[i], bh[j], acc[i][j], 0, 0, 0);
      }
  }
  #pragma unroll
  for (int j = 0; j < 2; ++j) {
    int col = col0 + wc*32 + j*16 + l16;
    float bv = bias[col];
    #pragma unroll
    for (int i = 0; i < 4; ++i) {
      int rowb = row0 + wr*64 + i*16 + quad*4;
      #pragma unroll
      for (int r = 0; r < 4; ++r)
        T1[(size_t)(rowb + r) * HIDDEN + col] = fmaxf(acc[i][j][r] + bv, 0.0f);
    }
  }
}

// ---------------- kernel 2: t1 GEMM + QKV GEMM, interleaved 1:3 ----------------
__global__ __launch_bounds__(256) void mega_gemm1(
    const short* __restrict__ qh, const short* __restrict__ ql,
    const short* __restrict__ w1h, const short* __restrict__ w1l,
    const float* __restrict__ inf1_b, float* __restrict__ T1,
    const short* __restrict__ Wq, const short* __restrict__ Wk,
    const short* __restrict__ Wv,
    const float* __restrict__ qb, const float* __restrict__ kb,
    const float* __restrict__ vb,
    short* __restrict__ Qp, short* __restrict__ Kp, short* __restrict__ Vp)
{
  __shared__ __attribute__((aligned(16))) short smem[12288];   // 24 KB union
  int blk = blockIdx.x;
  if ((blk & 3) == 3) {
    int id = blk >> 2;                         // [0,256)
    gemm_t1_body(smem, qh, ql, w1h, w1l, inf1_b, T1,
                 (id & 31) * 128, (id >> 5) * 64);
  } else {
    int id = (blk >> 2) * 3 + (blk & 3);       // [0,768)
    int row0 = (id & 31) * 128;
    int rest = id >> 5;                        // [0,24)
    int mat = rest >> 3, cb = rest & 7;
    const short* B   = (mat == 0) ? Wq : (mat == 1) ? Wk : Wv;
    const float* bia = (mat == 0) ? qb : (mat == 1) ? kb : vb;
    short* out       = (mat == 0) ? Qp : (mat == 1) ? Kp : Vp;
    // q scale folds D^-0.5 * log2(e) (flash softmax runs in exp2 domain)
    float scale      = (mat == 0) ? 0.18033688011112042f : 1.0f;
    gemm128_body<false>(smem, qh, B, bia, (void*)out, row0, cb * 128, scale);
  }
}

// ---------------- kernel 3: head-mask + V-transpose in one launch ----------------
__global__ __launch_bounds__(256) void mid_kernel(
    const float* __restrict__ T1, const float* __restrict__ inf2_w,
    const float* __restrict__ inf2_b, const float* __restrict__ head_sig,
    float* __restrict__ maskbuf,
    const short* __restrict__ Vp, short* __restrict__ VT)
{
  __shared__ __attribute__((aligned(16))) float fsm[16*HIDDEN + 16*SIGD + 16*NHEAD];
  int blk = blockIdx.x;
  const int tid = threadIdx.x;
  if (blk < 256) {
    // ---- head mask: t2 = t1 @ inf2_w^T + b ; s = t2 @ head_sig^T ; top-12 ----
    float (*t1s)[HIDDEN] = (float(*)[HIDDEN])fsm;
    float (*t2s)[SIGD]   = (float(*)[SIGD])(fsm + 16*HIDDEN);
    float (*ss)[NHEAD]   = (float(*)[NHEAD])(fsm + 16*HIDDEN + 16*SIGD);
    const int tok0 = blk * 16;
    {
      int row = tid >> 4, c0 = (tid & 15) * 32;
      const float* src = T1 + (size_t)(tok0 + row) * HIDDEN + c0;
      #pragma unroll
      for (int u = 0; u < 8; ++u)
        *(float4*)&t1s[row][c0 + u*4] = *(const float4*)(src + u*4);
    }
    __syncthreads();
    #pragma unroll
    for (int it = 0; it < 4; ++it) {
      int idx = tid + it * 256;
      int tok = idx >> 6, j = idx & 63;
      const float4* w4 = (const float4*)(inf2_w + (size_t)j * HIDDEN);
      const float4* t4 = (const float4*)(&t1s[tok][0]);
      float a = inf2_b[j];
      for (int k = 0; k < HIDDEN/4; ++k) {
        float4 wv = w4[k], tv = t4[k];
        a += tv.x*wv.x + tv.y*wv.y + tv.z*wv.z + tv.w*wv.w;
      }
      t2s[tok][j] = a;
    }
    __syncthreads();
    {
      int tok = tid >> 4, h = tid & 15;
      float a = 0.f;
      for (int d = 0; d < SIGD; ++d) a += t2s[tok][d] * head_sig[h*SIGD + d];
      ss[tok][h] = a;
    }
    __syncthreads();
    {
      int tok = tid >> 4, h = tid & 15;
      float sv = ss[tok][h];
      int cnt = 0;
      #pragma unroll
      for (int j = 0; j < NHEAD; ++j) cnt += (ss[tok][j] > sv) ? 1 : 0;
      int gt = tok0 + tok;
      int s = gt >> 1, b = gt & 1;             // token row = s*B + b
      maskbuf[((size_t)(b*NHEAD + h)) * S_LEN + s] = (cnt < KEEP) ? 1.0f : 0.0f;
    }
  } else {
    // ---- V transpose: Vp (token-major) -> VT[(b*16+h)*64+d][S_LEN] ----
    short (*tile)[72] = (short(*)[72])fsm;
    int t = blk - 256;                          // [0,1024)
    const int s0 = (t & 31) * 64, e0 = ((t >> 5) & 15) * 64, b = t >> 9;
    {
      int sr = tid >> 2, ec = (tid & 3) * 16;
      const short* src = Vp + (size_t)(s0 + sr) * 2048 + b * 1024 + e0 + ec;
      *(uint4*)&tile[sr][ec]     = *(const uint4*)src;
      *(uint4*)&tile[sr][ec + 8] = *(const uint4*)(src + 8);
    }
    __syncthreads();
    {
      int er = tid >> 2, sc = (tid & 3) * 16;
      unsigned pack[8];
      #pragma unroll
      for (int u = 0; u < 8; ++u) {
        unsigned lo = (unsigned short)tile[sc + 2*u][er];
        unsigned hi = (unsigned short)tile[sc + 2*u + 1][er];
        pack[u] = lo | (hi << 16);
      }
      short* dst = VT + (size_t)(b * 1024 + e0 + er) * 2048 + s0 + sc;
      *(uint4*)(dst)     = *(uint4*)&pack[0];
      *(uint4*)(dst + 8) = *(uint4*)&pack[4];
    }
  }
}

// ---------------- kernel 4: flash attention (exp2 domain) ----------------
// v6 = v5 staging/layout + SWAPPED-OPERAND MFMAs (T12 structure):
//  * QK^T computed as mfma(K,Q) -> S^T: each lane holds 32 kv-scores for ONE
//    q-row (q=l16). Softmax reductions become in-lane trees + 2 ds_bpermute
//    butterflies (lane^16, lane^32) -- replaces 8-row DPP reductions.
//  * P r-pairs are in-lane adjacent -> Ps written as 16 ds_write_b64/tile
//    (was 64 ds_write_b16), conflict-free under chunk^(l16&7).
//  * PV computed as mfma(V^T,P^T) -> O^T: V/Ps read patterns unchanged from
//    v5; output stays keyed q=l16 so alpha/l_i need no cross-lane traffic.
//  * LDS 64KB (K 16K + V 16K + Ps 32K, Q unioned), 2 blocks/CU, grid 512.
__global__ __launch_bounds__(256) void flash_attn(
    short* QpOg, const short* __restrict__ Kp, const short* __restrict__ VT,
    const float* __restrict__ maskbuf)
{
  __shared__ __attribute__((aligned(16))) short smem[32768];   // 64 KB exactly
  short* KsL = smem;            // [128 kv][64 d]   linear, chunk^=(row&7)
  short* VtL = smem + 8192;     // [64 d][128 kv]   linear, chunk^=(row&7)
  short* PsB = smem + 16384;    // 4 waves x [2 h2][16 q][128 kv], chunk^=(q&7)
  short* Qs  = smem + 16384;    // [128 q][64 d] union with Ps (pre-loop only)

  const int bh = blockIdx.x;
  const int b = bh >> 4, h = bh & 15;
  const int q0 = blockIdx.y * 128;
  const int tid = threadIdx.x;
  const int wave = tid >> 6, lane = tid & 63;
  const int quad = lane >> 4, l16 = lane & 15;
  const size_t colbase = (size_t)b * EDIM + h * DHEAD;
  const size_t rstride = (size_t)BATCH * EDIM;   // 2048
  short* Psw = PsB + wave * 4096;

  const int ix16 = (lane ^ 16) << 2;             // bpermute byte indices
  const int ix32 = (lane ^ 32) << 2;

  {  // ---- stage Q (swizzled), once ----
    int row = tid >> 1;
    int cb  = (tid & 1) * 4;
    const short* src = QpOg + (size_t)(q0 + row) * rstride + colbase + cb * 8;
    #pragma unroll
    for (int u = 0; u < 4; ++u) {
      uint4 v = *(const uint4*)(src + u * 8);
      *(uint4*)&Qs[row * 64 + (((cb + u) ^ (row & 7)) * 8)] = v;
    }
  }
  __syncthreads();
  bf16x8 aq[2][2];
  #pragma unroll
  for (int h2 = 0; h2 < 2; ++h2)
    #pragma unroll
    for (int dh = 0; dh < 2; ++dh) {
      int row = wave * 32 + h2 * 16 + l16;       // row&7 == l16&7
      aq[h2][dh] = *(const bf16x8*)&Qs[row * 64 + (((dh * 4 + quad) ^ (l16 & 7)) * 8)];
    }

  // staging lane constants (identical to v5)
  const int kxor = (lane & 7) ^ (lane >> 3);      // K: chunk ^ row&7
  const short* gKbase = Kp + colbase + (size_t)(wave * 32 + (lane >> 3)) * rstride + kxor * 8;
  short* ldsK = KsL + wave * 2048;
  const int vrow_l = lane >> 4;
  short* ldsV = VtL + wave * 2048;

  float m_i[2] = {-1e30f, -1e30f};
  float l_i[2] = {0.f, 0.f};
  f32x4 oacc[2][4];
  #pragma unroll
  for (int h2 = 0; h2 < 2; ++h2)
    #pragma unroll
    for (int dt = 0; dt < 4; ++dt) oacc[h2][dt] = f32x4{0.f, 0.f, 0.f, 0.f};

  for (int kv0 = 0; kv0 < S_LEN; kv0 += 128) {
    __syncthreads();                 // all waves done reading previous tile
    #pragma unroll
    for (int i = 0; i < 4; ++i) {
      gl_lds16(gKbase + (size_t)(kv0 + i * 8) * rstride, ldsK + i * 512);
      int vrow = wave * 16 + i * 4 + vrow_l;
      int vx = (lane & 15) ^ ((i & 1) * 4 + vrow_l);
      gl_lds16(VT + (size_t)(bh * 64 + vrow) * S_LEN + kv0 + vx * 8, ldsV + i * 512);
    }
    asm volatile("s_waitcnt vmcnt(0)" ::: "memory");
    __syncthreads();                 // staged tile visible to all waves

    // ---- QK^T swapped: sacc[h2][c][r] = S^T[kv=c*16+quad*4+r][q=h2-set l16] ----
    f32x4 sacc[2][8];
    #pragma unroll
    for (int h2 = 0; h2 < 2; ++h2)
      #pragma unroll
      for (int c = 0; c < 8; ++c) sacc[h2][c] = f32x4{0.f, 0.f, 0.f, 0.f};
    #pragma unroll
    for (int c = 0; c < 8; ++c) {
      const short* kr = &KsL[(c * 16 + l16) * 64];          // row&7 == l16&7
      bf16x8 k0 = *(const bf16x8*)&kr[((quad     ^ (l16 & 7)) * 8)];
      bf16x8 k1 = *(const bf16x8*)&kr[(((4 + quad) ^ (l16 & 7)) * 8)];
      #pragma unroll
      for (int h2 = 0; h2 < 2; ++h2) {
        sacc[h2][c] = __builtin_amdgcn_mfma_f32_16x16x32_bf16(k0, aq[h2][0], sacc[h2][c], 0, 0, 0);
        sacc[h2][c] = __builtin_amdgcn_mfma_f32_16x16x32_bf16(k1, aq[h2][1], sacc[h2][c], 0, 0, 0);
      }
    }

    // ---- online softmax: per lane, one q-row per h2, 32 kv values in-lane ----
    #pragma unroll
    for (int h2 = 0; h2 < 2; ++h2) {
      float vm = fmaxf(fmaxf(sacc[h2][0][0], sacc[h2][0][1]),
                       fmaxf(sacc[h2][0][2], sacc[h2][0][3]));
      #pragma unroll
      for (int c = 1; c < 8; ++c)
        vm = fmaxf(vm, fmaxf(fmaxf(sacc[h2][c][0], sacc[h2][c][1]),
                             fmaxf(sacc[h2][c][2], sacc[h2][c][3])));
      vm = fmaxf(vm, bperm_f(ix16, vm));
      vm = fmaxf(vm, bperm_f(ix32, vm));
      float mnew = fmaxf(m_i[h2], vm);
      float alpha = fexp2(m_i[h2] - mnew);
      float rs = 0.f;
      short* pw = Psw + h2 * 2048 + l16 * 128 + (quad & 1) * 4;
      #pragma unroll
      for (int c = 0; c < 8; ++c) {
        float e0 = fexp2(sacc[h2][c][0] - mnew);
        float e1 = fexp2(sacc[h2][c][1] - mnew);
        float e2 = fexp2(sacc[h2][c][2] - mnew);
        float e3 = fexp2(sacc[h2][c][3] - mnew);
        unsigned lo = __builtin_amdgcn_perm(
            __builtin_bit_cast(unsigned, e1),
            __builtin_bit_cast(unsigned, e0), 0x07060302u);
        unsigned hi = __builtin_amdgcn_perm(
            __builtin_bit_cast(unsigned, e3),
            __builtin_bit_cast(unsigned, e2), 0x07060302u);
        int ch = (c * 2 + (quad >> 1)) ^ (l16 & 7);
        uint2 w2; w2.x = lo; w2.y = hi;
        *(uint2*)(pw + ch * 8) = w2;             // cols c*16+quad*4 .. +3
        rs += (e0 + e1) + (e2 + e3);
      }
      rs += bperm_f(ix16, rs);
      rs += bperm_f(ix32, rs);
      l_i[h2] = l_i[h2] * alpha + rs;
      m_i[h2] = mnew;
      #pragma unroll
      for (int dt = 0; dt < 4; ++dt) {
        oacc[h2][dt][0] *= alpha; oacc[h2][dt][1] *= alpha;
        oacc[h2][dt][2] *= alpha; oacc[h2][dt][3] *= alpha;
      }
    }
    asm volatile("s_waitcnt lgkmcnt(0)" ::: "memory");   // Ps visible (same wave)

    // ---- PV swapped: oacc[h2][dt] = O^T fragments; V/Ps reads as v5 ----
    #pragma unroll
    for (int ks = 0; ks < 4; ++ks) {
      const short* pr = Psw + l16 * 128 + (((ks * 4 + quad) ^ (l16 & 7)) * 8);
      bf16x8 ps0 = *(const bf16x8*)pr;
      bf16x8 ps1 = *(const bf16x8*)(pr + 2048);
      #pragma unroll
      for (int dt = 0; dt < 4; ++dt) {
        bf16x8 bb = *(const bf16x8*)&VtL[(dt * 16 + l16) * 128 +
                                         (((ks * 4 + quad) ^ (l16 & 7)) * 8)];
        oacc[0][dt] = __builtin_amdgcn_mfma_f32_16x16x32_bf16(bb, ps0, oacc[0][dt], 0, 0, 0);
        oacc[1][dt] = __builtin_amdgcn_mfma_f32_16x16x32_bf16(bb, ps1, oacc[1][dt], 0, 0, 0);
      }
    }
  }

  // ---- epilogue: O^T[d = dt*16+quad*4+r][q = l16-keyed]; pack d-pairs ----
  #pragma unroll
  for (int h2 = 0; h2 < 2; ++h2) {
    int q = q0 + wave * 32 + h2 * 16 + l16;
    float mk = maskbuf[((size_t)(b * NHEAD + h)) * S_LEN + q];
    float sc = mk / l_i[h2];
    short* dst = QpOg + (size_t)q * rstride + colbase;
    #pragma unroll
    for (int dt = 0; dt < 4; ++dt) {
      #pragma unroll
      for (int p = 0; p < 2; ++p) {
        unsigned lo = (unsigned short)f2bf(oacc[h2][dt][2*p]     * sc);
        unsigned hi = (unsigned short)f2bf(oacc[h2][dt][2*p + 1] * sc);
        *(unsigned*)(dst + dt*16 + quad*4 + 2*p) = lo | (hi << 16);
      }
    }
  }
}

// ---------------- kernel 5: out projection ----------------
__global__ __launch_bounds__(256) void gemm_out(
    const short* __restrict__ A, const short* __restrict__ W,
    const float* __restrict__ bias, float* __restrict__ out)
{
  __shared__ __attribute__((aligned(16))) short smem[8192];
  gemm128_body<true>(smem, A, W, bias, (void*)out,
                     blockIdx.x * 128, blockIdx.y * 128, 1.0f);
}

extern "C" void kernel_launch(void* const* d_in, const int* in_sizes, int n_in,
                              void* d_out, int out_size, void* d_ws, size_t ws_size,
                              hipStream_t stream)
{
  const float* query   = (const float*)d_in[0];
  const float* q_w     = (const float*)d_in[1];
  const float* q_b     = (const float*)d_in[2];
  const float* k_w     = (const float*)d_in[3];
  const float* k_b     = (const float*)d_in[4];
  const float* v_w     = (const float*)d_in[5];
  const float* v_b     = (const float*)d_in[6];
  const float* out_w   = (const float*)d_in[7];
  const float* out_b   = (const float*)d_in[8];
  const float* inf1_w  = (const float*)d_in[9];
  const float* inf1_b  = (const float*)d_in[10];
  const float* inf2_w  = (const float*)d_in[11];
  const float* inf2_b  = (const float*)d_in[12];
  const float* head_sig= (const float*)d_in[13];

  char* ws = (char*)d_ws;
  short* qh      = (short*)(ws);
  short* VTb     = (short*)(ws);
  short* ql      = (short*)(ws + (size_t)( 8u<<20));
  float* maskbuf = (float*)(ws + (size_t)( 8u<<20));
  short* Qp      = (short*)(ws + (size_t)(16u<<20));
  short* Kp      = (short*)(ws + (size_t)(24u<<20));
  short* Vp      = (short*)(ws + (size_t)(32u<<20));
  short* Wo      = (short*)(ws + (size_t)(40u<<20));
  char* ob = (char*)d_out;
  float* T1  = (float*)(ob);
  short* w1h = (short*)(ob + (size_t)( 8u<<20));
  short* w1l = (short*)(ob + (size_t)( 9u<<20));
  short* Wq  = (short*)(ob + (size_t)(10u<<20));
  short* Wk  = (short*)(ob + (size_t)(12u<<20));
  short* Wv  = (short*)(ob + (size_t)(14u<<20));
  float* out = (float*)d_out;

  dim3 blk(256);
  cvt_all<<<dim3(8704), blk, 0, stream>>>(query, inf1_w, q_w, k_w, v_w, out_w,
                                          qh, ql, w1h, w1l, Wq, Wk, Wv, Wo);
  mega_gemm1<<<dim3(1024), blk, 0, stream>>>(qh, ql, w1h, w1l, inf1_b, T1,
                                             Wq, Wk, Wv, q_b, k_b, v_b, Qp, Kp, Vp);
  mid_kernel<<<dim3(1280), blk, 0, stream>>>(T1, inf2_w, inf2_b, head_sig, maskbuf,
                                             Vp, VTb);
  flash_attn<<<dim3(32, 16), blk, 0, stream>>>(Qp, Kp, VTb, maskbuf);
  gemm_out<<<dim3(32, 8), blk, 0, stream>>>(Qp, Wo, out_b, out);
}

// Round 6
// 302.775 us; speedup vs baseline: 1.1924x; 1.0232x over previous
//
#include <hip/hip_runtime.h>
#include <hip/hip_bf16.h>

#define S_LEN 2048
#define BATCH 2
#define EDIM 1024
#define NHEAD 16
#define DHEAD 64
#define HIDDEN 512
#define SIGD 64
#define KEEP 12           // NUM_HEADS - INACTIVE

typedef __attribute__((ext_vector_type(8))) short bf16x8;
typedef __attribute__((ext_vector_type(4))) float f32x4;

static __device__ __forceinline__ float bf2f(short s) {
  unsigned int u = ((unsigned int)(unsigned short)s) << 16;
  float f; __builtin_memcpy(&f, &u, 4); return f;
}
static __device__ __forceinline__ short f2bf(float f) {
  unsigned int u; __builtin_memcpy(&u, &f, 4);
  u += 0x7fffu + ((u >> 16) & 1u);   // round-to-nearest-even
  return (short)(u >> 16);
}

#if __has_builtin(__builtin_amdgcn_exp2f)
static __device__ __forceinline__ float fexp2(float x) { return __builtin_amdgcn_exp2f(x); }
#else
static __device__ __forceinline__ float fexp2(float x) { return exp2f(x); }
#endif

// async global->LDS, 16B per lane. LDS dest is wave-uniform base + lane*16.
static __device__ __forceinline__ void gl_lds16(const short* g, short* l) {
  __builtin_amdgcn_global_load_lds(
      (const __attribute__((address_space(1))) unsigned int*)g,
      (__attribute__((address_space(3))) unsigned int*)l, 16, 0, 0);
}

static __device__ __forceinline__ float bperm_f(int idx, float v) {
  return __builtin_bit_cast(float,
      __builtin_amdgcn_ds_bpermute(idx, __builtin_bit_cast(int, v)));
}

// ---------------- kernel 1: ALL dtype conversions in one launch ----------------
// [0,4096): query hi/lo split. [4096,4608): inf1_w hi/lo split.
// [4608,5632) Wq, [5632,6656) Wk, [6656,7680) Wv, [7680,8704) Wo (plain bf16).
__global__ __launch_bounds__(256) void cvt_all(
    const float* __restrict__ query, const float* __restrict__ inf1_w,
    const float* __restrict__ qw, const float* __restrict__ kw,
    const float* __restrict__ vw, const float* __restrict__ ow,
    short* __restrict__ qh, short* __restrict__ ql,
    short* __restrict__ w1h, short* __restrict__ w1l,
    short* __restrict__ Wq, short* __restrict__ Wk,
    short* __restrict__ Wv, short* __restrict__ Wo)
{
  int blk = blockIdx.x;
  if (blk < 4608) {              // split sections
    const float* in; short *oh, *ol; int i;
    if (blk < 4096) { in = query;  oh = qh;  ol = ql;  i = (blk * 256 + threadIdx.x) * 4; }
    else            { in = inf1_w; oh = w1h; ol = w1l; i = ((blk - 4096) * 256 + threadIdx.x) * 4; }
    float4 f = *(const float4*)(in + i);
    union { short s[4]; uint2 v; } uh, ul;
    float x[4] = {f.x, f.y, f.z, f.w};
    #pragma unroll
    for (int u = 0; u < 4; ++u) {
      short h = f2bf(x[u]);
      uh.s[u] = h;
      ul.s[u] = f2bf(x[u] - bf2f(h));
    }
    *(uint2*)(oh + i) = uh.v;
    *(uint2*)(ol + i) = ul.v;
  } else {                       // plain bf16 sections (1024 blocks each)
    int t = blk - 4608;
    int mat = t >> 10, sub = t & 1023;
    const float* in = (mat == 0) ? qw : (mat == 1) ? kw : (mat == 2) ? vw : ow;
    short* out      = (mat == 0) ? Wq : (mat == 1) ? Wk : (mat == 2) ? Wv : Wo;
    int i = (sub * 256 + threadIdx.x) * 4;
    float4 f = *(const float4*)(in + i);
    union { short s[4]; uint2 v; } u;
    u.s[0] = f2bf(f.x); u.s[1] = f2bf(f.y); u.s[2] = f2bf(f.z); u.s[3] = f2bf(f.w);
    *(uint2*)(out + i) = u.v;
  }
}

// ---------------- m97-style 128x128 GEMM body (smem passed in) ----------------
static __device__ __forceinline__ void gemm128_body(
    short* smem,
    const short* __restrict__ A, const short* __restrict__ B,
    const float* __restrict__ bias, short* __restrict__ outv,
    int row0, int col0, float scale)
{
  short* As = smem;              // 128*32
  short* Bs = smem + 128*32;     // 128*32
  const int tid  = threadIdx.x;
  const int wave = tid >> 6, lane = tid & 63;
  const int quad = lane >> 4, l16 = lane & 15;
  const int wr = wave >> 1, wc = wave & 1;
  const int lr = lane >> 2, lc8 = (lane & 3) * 8;

  const short* gA = A + (size_t)(row0 + wave*16 + lr) * EDIM + lc8;
  const short* gB = B + (size_t)(col0 + wave*16 + lr) * EDIM + lc8;
  short* lA = As + wave*512;
  short* lB = Bs + wave*512;

  f32x4 acc[4][4] = {};
  gl_lds16(gA, lA);  gl_lds16(gA + 64*EDIM, lA + 64*32);
  gl_lds16(gB, lB);  gl_lds16(gB + 64*EDIM, lB + 64*32);

  for (int k0 = 0; k0 < EDIM; k0 += 32) {
    __syncthreads();
    bf16x8 af[4], bfr[4];
    #pragma unroll
    for (int i = 0; i < 4; ++i)
      af[i] = *(const bf16x8*)&As[(wr*64 + i*16 + l16)*32 + quad*8];
    #pragma unroll
    for (int j = 0; j < 4; ++j)
      bfr[j] = *(const bf16x8*)&Bs[(wc*64 + j*16 + l16)*32 + quad*8];
    __syncthreads();
    if (k0 + 32 < EDIM) {
      const short* gA2 = gA + k0 + 32;
      const short* gB2 = gB + k0 + 32;
      gl_lds16(gA2, lA);  gl_lds16(gA2 + 64*EDIM, lA + 64*32);
      gl_lds16(gB2, lB);  gl_lds16(gB2 + 64*EDIM, lB + 64*32);
    }
    #pragma unroll
    for (int i = 0; i < 4; ++i)
      #pragma unroll
      for (int j = 0; j < 4; ++j)
        acc[i][j] = __builtin_amdgcn_mfma_f32_16x16x32_bf16(af[i], bfr[j], acc[i][j], 0, 0, 0);
  }
  #pragma unroll
  for (int j = 0; j < 4; ++j) {
    int col = col0 + wc*64 + j*16 + l16;
    float bv = bias[col];
    #pragma unroll
    for (int i = 0; i < 4; ++i) {
      int rowb = row0 + wr*64 + i*16 + quad*4;
      #pragma unroll
      for (int r = 0; r < 4; ++r) {
        float v = (acc[i][j][r] + bv) * scale;
        outv[(size_t)(rowb + r) * EDIM + col] = f2bf(v);
      }
    }
  }
}

// t1 body: 128x64 tile, hi/lo-split (3 MFMAs, fp32-accurate), relu -> T1 fp32.
static __device__ __forceinline__ void gemm_t1_body(
    short* smem,
    const short* __restrict__ Agh, const short* __restrict__ Agl,
    const short* __restrict__ Bgh, const short* __restrict__ Bgl,
    const float* __restrict__ bias, float* __restrict__ T1,
    int row0, int col0)
{
  short* Ah = smem;              // 128*32
  short* Al = smem + 4096;      // 128*32
  short* Bh = smem + 8192;      // 64*32
  short* Bl = smem + 10240;     // 64*32
  const int tid  = threadIdx.x;
  const int wave = tid >> 6, lane = tid & 63;
  const int quad = lane >> 4, l16 = lane & 15;
  const int wr = wave >> 1, wc = wave & 1;
  const int lr = lane >> 2, lc8 = (lane & 3) * 8;

  const short* gAh = Agh + (size_t)(row0 + wave*16 + lr) * EDIM + lc8;
  const short* gAl = Agl + (size_t)(row0 + wave*16 + lr) * EDIM + lc8;
  const short* gBh = Bgh + (size_t)(col0 + wave*16 + lr) * EDIM + lc8;
  const short* gBl = Bgl + (size_t)(col0 + wave*16 + lr) * EDIM + lc8;
  short* lAh = Ah + wave*512;  short* lAl = Al + wave*512;
  short* lBh = Bh + wave*512;  short* lBl = Bl + wave*512;

  f32x4 acc[4][2] = {};
  gl_lds16(gAh, lAh);  gl_lds16(gAh + 64*EDIM, lAh + 64*32);
  gl_lds16(gAl, lAl);  gl_lds16(gAl + 64*EDIM, lAl + 64*32);
  gl_lds16(gBh, lBh);  gl_lds16(gBl, lBl);

  for (int k0 = 0; k0 < EDIM; k0 += 32) {
    __syncthreads();
    bf16x8 ah[4], al[4], bh[2], bl[2];
    #pragma unroll
    for (int i = 0; i < 4; ++i) {
      ah[i] = *(const bf16x8*)&Ah[(wr*64 + i*16 + l16)*32 + quad*8];
      al[i] = *(const bf16x8*)&Al[(wr*64 + i*16 + l16)*32 + quad*8];
    }
    #pragma unroll
    for (int j = 0; j < 2; ++j) {
      bh[j] = *(const bf16x8*)&Bh[(wc*32 + j*16 + l16)*32 + quad*8];
      bl[j] = *(const bf16x8*)&Bl[(wc*32 + j*16 + l16)*32 + quad*8];
    }
    __syncthreads();
    if (k0 + 32 < EDIM) {
      const short* p;
      p = gAh + k0 + 32;  gl_lds16(p, lAh);  gl_lds16(p + 64*EDIM, lAh + 64*32);
      p = gAl + k0 + 32;  gl_lds16(p, lAl);  gl_lds16(p + 64*EDIM, lAl + 64*32);
      gl_lds16(gBh + k0 + 32, lBh);  gl_lds16(gBl + k0 + 32, lBl);
    }
    #pragma unroll
    for (int i = 0; i < 4; ++i)
      #pragma unroll
      for (int j = 0; j < 2; ++j) {
        acc[i][j] = __builtin_amdgcn_mfma_f32_16x16x32_bf16(ah[i], bh[j], acc[i][j], 0, 0, 0);
        acc[i][j] = __builtin_amdgcn_mfma_f32_16x16x32_bf16(ah[i], bl[j], acc[i][j], 0, 0, 0);
        acc[i][j] = __builtin_amdgcn_mfma_f32_16x16x32_bf16(al[i], bh[j], acc[i][j], 0, 0, 0);
      }
  }
  #pragma unroll
  for (int j = 0; j < 2; ++j) {
    int col = col0 + wc*32 + j*16 + l16;
    float bv = bias[col];
    #pragma unroll
    for (int i = 0; i < 4; ++i) {
      int rowb = row0 + wr*64 + i*16 + quad*4;
      #pragma unroll
      for (int r = 0; r < 4; ++r)
        T1[(size_t)(rowb + r) * HIDDEN + col] = fmaxf(acc[i][j][r] + bv, 0.0f);
    }
  }
}

// ---------------- kernel 2: t1 GEMM + QKV GEMM, interleaved 1:3 ----------------
// __launch_bounds__(256,4): cap unified regs at 128 (acc=64 AGPR + <=64 VGPR)
// so 4 blocks/CU fit -> the full 1024-block grid is co-resident (kills the
// 1.33-round tail seen at 160 regs / 3 blocks/CU).
__global__ __launch_bounds__(256, 4) void mega_gemm1(
    const short* __restrict__ qh, const short* __restrict__ ql,
    const short* __restrict__ w1h, const short* __restrict__ w1l,
    const float* __restrict__ inf1_b, float* __restrict__ T1,
    const short* __restrict__ Wq, const short* __restrict__ Wk,
    const short* __restrict__ Wv,
    const float* __restrict__ qb, const float* __restrict__ kb,
    const float* __restrict__ vb,
    short* __restrict__ Qp, short* __restrict__ Kp, short* __restrict__ Vp)
{
  __shared__ __attribute__((aligned(16))) short smem[12288];   // 24 KB union
  int blk = blockIdx.x;
  if ((blk & 3) == 3) {
    int id = blk >> 2;                         // [0,256)
    gemm_t1_body(smem, qh, ql, w1h, w1l, inf1_b, T1,
                 (id & 31) * 128, (id >> 5) * 64);
  } else {
    int id = (blk >> 2) * 3 + (blk & 3);       // [0,768)
    int row0 = (id & 31) * 128;
    int rest = id >> 5;                        // [0,24)
    int mat = rest >> 3, cb = rest & 7;
    const short* B   = (mat == 0) ? Wq : (mat == 1) ? Wk : Wv;
    const float* bia = (mat == 0) ? qb : (mat == 1) ? kb : vb;
    short* out       = (mat == 0) ? Qp : (mat == 1) ? Kp : Vp;
    // q scale folds D^-0.5 * log2(e) (flash softmax runs in exp2 domain)
    float scale      = (mat == 0) ? 0.18033688011112042f : 1.0f;
    gemm128_body(smem, qh, B, bia, out, row0, cb * 128, scale);
  }
}

// ---------------- kernel 3: head-mask + V-transpose in one launch ----------------
// v2: mask re-tiled to 8 tokens/block (512 blocks, ~19KB LDS, ILP-2 dot chains)
// interleaved 1:2 with the 1024 transpose blocks -> every CU gets a mix and
// the heavy mask work is spread at 6 blocks/CU instead of straggling at 1/CU.
__global__ __launch_bounds__(256) void mid_kernel(
    const float* __restrict__ T1, const float* __restrict__ inf2_w,
    const float* __restrict__ inf2_b, const float* __restrict__ head_sig,
    float* __restrict__ maskbuf,
    const short* __restrict__ Vp, short* __restrict__ VT)
{
  __shared__ __attribute__((aligned(16))) float fsm[8*HIDDEN + 8*SIGD + 8*NHEAD];
  int blk = blockIdx.x;
  const int g = blk / 3, r3 = blk % 3;
  const int tid = threadIdx.x;
  if (r3 == 2) {
    // ---- head mask (8 tokens): t2 = t1 @ inf2_w^T + b ; s = t2 @ head_sig^T ----
    float (*t1s)[HIDDEN] = (float(*)[HIDDEN])fsm;
    float (*t2s)[SIGD]   = (float(*)[SIGD])(fsm + 8*HIDDEN);
    float (*ss)[NHEAD]   = (float(*)[NHEAD])(fsm + 8*HIDDEN + 8*SIGD);
    const int tok0 = g * 8;
    {
      int row = tid >> 5, c0 = (tid & 31) * 16;
      const float* src = T1 + (size_t)(tok0 + row) * HIDDEN + c0;
      #pragma unroll
      for (int u = 0; u < 4; ++u)
        *(float4*)&t1s[row][c0 + u*4] = *(const float4*)(src + u*4);
    }
    __syncthreads();
    {
      int tok = tid >> 5, j0 = (tid & 31) * 2;
      const float4* w0 = (const float4*)(inf2_w + (size_t)j0 * HIDDEN);
      const float4* w1 = (const float4*)(inf2_w + (size_t)(j0 + 1) * HIDDEN);
      const float4* t4 = (const float4*)(&t1s[tok][0]);
      float a0 = inf2_b[j0], a1 = inf2_b[j0 + 1];
      for (int k = 0; k < HIDDEN/4; ++k) {
        float4 tv = t4[k];
        float4 v0 = w0[k], v1 = w1[k];
        a0 += tv.x*v0.x + tv.y*v0.y + tv.z*v0.z + tv.w*v0.w;
        a1 += tv.x*v1.x + tv.y*v1.y + tv.z*v1.z + tv.w*v1.w;
      }
      t2s[tok][j0] = a0; t2s[tok][j0 + 1] = a1;
    }
    __syncthreads();
    if (tid < 128) {
      int tok = tid >> 4, h = tid & 15;
      float a = 0.f;
      for (int d = 0; d < SIGD; ++d) a += t2s[tok][d] * head_sig[h*SIGD + d];
      ss[tok][h] = a;
    }
    __syncthreads();
    if (tid < 128) {
      int tok = tid >> 4, h = tid & 15;
      float sv = ss[tok][h];
      int cnt = 0;
      #pragma unroll
      for (int j = 0; j < NHEAD; ++j) cnt += (ss[tok][j] > sv) ? 1 : 0;
      int gt = tok0 + tok;
      int s = gt >> 1, b = gt & 1;             // token row = s*B + b
      maskbuf[((size_t)(b*NHEAD + h)) * S_LEN + s] = (cnt < KEEP) ? 1.0f : 0.0f;
    }
  } else {
    // ---- V transpose: Vp (token-major) -> VT[(b*16+h)*64+d][S_LEN] ----
    short (*tile)[72] = (short(*)[72])fsm;
    int t = g * 2 + r3;                         // [0,1024)
    const int s0 = (t & 31) * 64, e0 = ((t >> 5) & 15) * 64, b = t >> 9;
    {
      int sr = tid >> 2, ec = (tid & 3) * 16;
      const short* src = Vp + (size_t)(s0 + sr) * 2048 + b * 1024 + e0 + ec;
      *(uint4*)&tile[sr][ec]     = *(const uint4*)src;
      *(uint4*)&tile[sr][ec + 8] = *(const uint4*)(src + 8);
    }
    __syncthreads();
    {
      int er = tid >> 2, sc = (tid & 3) * 16;
      unsigned pack[8];
      #pragma unroll
      for (int u = 0; u < 8; ++u) {
        unsigned lo = (unsigned short)tile[sc + 2*u][er];
        unsigned hi = (unsigned short)tile[sc + 2*u + 1][er];
        pack[u] = lo | (hi << 16);
      }
      short* dst = VT + (size_t)(b * 1024 + e0 + er) * 2048 + s0 + sc;
      *(uint4*)(dst)     = *(uint4*)&pack[0];
      *(uint4*)(dst + 8) = *(uint4*)&pack[4];
    }
  }
}

// ---------------- kernel 4: flash attention (exp2 domain) ----------------
// v6 (unchanged from R5): swapped-operand MFMAs, per-lane softmax, gl_lds
// staging with XOR-swizzled source, 64KB LDS, grid 512 = 2/CU zero-tail.
__global__ __launch_bounds__(256) void flash_attn(
    short* QpOg, const short* __restrict__ Kp, const short* __restrict__ VT,
    const float* __restrict__ maskbuf)
{
  __shared__ __attribute__((aligned(16))) short smem[32768];   // 64 KB exactly
  short* KsL = smem;            // [128 kv][64 d]   linear, chunk^=(row&7)
  short* VtL = smem + 8192;     // [64 d][128 kv]   linear, chunk^=(row&7)
  short* PsB = smem + 16384;    // 4 waves x [2 h2][16 q][128 kv], chunk^=(q&7)
  short* Qs  = smem + 16384;    // [128 q][64 d] union with Ps (pre-loop only)

  const int bh = blockIdx.x;
  const int b = bh >> 4, h = bh & 15;
  const int q0 = blockIdx.y * 128;
  const int tid = threadIdx.x;
  const int wave = tid >> 6, lane = tid & 63;
  const int quad = lane >> 4, l16 = lane & 15;
  const size_t colbase = (size_t)b * EDIM + h * DHEAD;
  const size_t rstride = (size_t)BATCH * EDIM;   // 2048
  short* Psw = PsB + wave * 4096;

  const int ix16 = (lane ^ 16) << 2;             // bpermute byte indices
  const int ix32 = (lane ^ 32) << 2;

  {  // ---- stage Q (swizzled), once ----
    int row = tid >> 1;
    int cb  = (tid & 1) * 4;
    const short* src = QpOg + (size_t)(q0 + row) * rstride + colbase + cb * 8;
    #pragma unroll
    for (int u = 0; u < 4; ++u) {
      uint4 v = *(const uint4*)(src + u * 8);
      *(uint4*)&Qs[row * 64 + (((cb + u) ^ (row & 7)) * 8)] = v;
    }
  }
  __syncthreads();
  bf16x8 aq[2][2];
  #pragma unroll
  for (int h2 = 0; h2 < 2; ++h2)
    #pragma unroll
    for (int dh = 0; dh < 2; ++dh) {
      int row = wave * 32 + h2 * 16 + l16;       // row&7 == l16&7
      aq[h2][dh] = *(const bf16x8*)&Qs[row * 64 + (((dh * 4 + quad) ^ (l16 & 7)) * 8)];
    }

  // staging lane constants
  const int kxor = (lane & 7) ^ (lane >> 3);      // K: chunk ^ row&7
  const short* gKbase = Kp + colbase + (size_t)(wave * 32 + (lane >> 3)) * rstride + kxor * 8;
  short* ldsK = KsL + wave * 2048;
  const int vrow_l = lane >> 4;
  short* ldsV = VtL + wave * 2048;

  float m_i[2] = {-1e30f, -1e30f};
  float l_i[2] = {0.f, 0.f};
  f32x4 oacc[2][4];
  #pragma unroll
  for (int h2 = 0; h2 < 2; ++h2)
    #pragma unroll
    for (int dt = 0; dt < 4; ++dt) oacc[h2][dt] = f32x4{0.f, 0.f, 0.f, 0.f};

  for (int kv0 = 0; kv0 < S_LEN; kv0 += 128) {
    __syncthreads();                 // all waves done reading previous tile
    #pragma unroll
    for (int i = 0; i < 4; ++i) {
      gl_lds16(gKbase + (size_t)(kv0 + i * 8) * rstride, ldsK + i * 512);
      int vrow = wave * 16 + i * 4 + vrow_l;
      int vx = (lane & 15) ^ ((i & 1) * 4 + vrow_l);
      gl_lds16(VT + (size_t)(bh * 64 + vrow) * S_LEN + kv0 + vx * 8, ldsV + i * 512);
    }
    asm volatile("s_waitcnt vmcnt(0)" ::: "memory");
    __syncthreads();                 // staged tile visible to all waves

    // ---- QK^T swapped: sacc[h2][c][r] = S^T[kv=c*16+quad*4+r][q=h2-set l16] ----
    f32x4 sacc[2][8];
    #pragma unroll
    for (int h2 = 0; h2 < 2; ++h2)
      #pragma unroll
      for (int c = 0; c < 8; ++c) sacc[h2][c] = f32x4{0.f, 0.f, 0.f, 0.f};
    #pragma unroll
    for (int c = 0; c < 8; ++c) {
      const short* kr = &KsL[(c * 16 + l16) * 64];          // row&7 == l16&7
      bf16x8 k0 = *(const bf16x8*)&kr[((quad     ^ (l16 & 7)) * 8)];
      bf16x8 k1 = *(const bf16x8*)&kr[(((4 + quad) ^ (l16 & 7)) * 8)];
      #pragma unroll
      for (int h2 = 0; h2 < 2; ++h2) {
        sacc[h2][c] = __builtin_amdgcn_mfma_f32_16x16x32_bf16(k0, aq[h2][0], sacc[h2][c], 0, 0, 0);
        sacc[h2][c] = __builtin_amdgcn_mfma_f32_16x16x32_bf16(k1, aq[h2][1], sacc[h2][c], 0, 0, 0);
      }
    }

    // ---- online softmax: per lane, one q-row per h2, 32 kv values in-lane ----
    #pragma unroll
    for (int h2 = 0; h2 < 2; ++h2) {
      float vm = fmaxf(fmaxf(sacc[h2][0][0], sacc[h2][0][1]),
                       fmaxf(sacc[h2][0][2], sacc[h2][0][3]));
      #pragma unroll
      for (int c = 1; c < 8; ++c)
        vm = fmaxf(vm, fmaxf(fmaxf(sacc[h2][c][0], sacc[h2][c][1]),
                             fmaxf(sacc[h2][c][2], sacc[h2][c][3])));
      vm = fmaxf(vm, bperm_f(ix16, vm));
      vm = fmaxf(vm, bperm_f(ix32, vm));
      float mnew = fmaxf(m_i[h2], vm);
      float alpha = fexp2(m_i[h2] - mnew);
      float rs = 0.f;
      short* pw = Psw + h2 * 2048 + l16 * 128 + (quad & 1) * 4;
      #pragma unroll
      for (int c = 0; c < 8; ++c) {
        float e0 = fexp2(sacc[h2][c][0] - mnew);
        float e1 = fexp2(sacc[h2][c][1] - mnew);
        float e2 = fexp2(sacc[h2][c][2] - mnew);
        float e3 = fexp2(sacc[h2][c][3] - mnew);
        unsigned lo = __builtin_amdgcn_perm(
            __builtin_bit_cast(unsigned, e1),
            __builtin_bit_cast(unsigned, e0), 0x07060302u);
        unsigned hi = __builtin_amdgcn_perm(
            __builtin_bit_cast(unsigned, e3),
            __builtin_bit_cast(unsigned, e2), 0x07060302u);
        int ch = (c * 2 + (quad >> 1)) ^ (l16 & 7);
        uint2 w2; w2.x = lo; w2.y = hi;
        *(uint2*)(pw + ch * 8) = w2;             // cols c*16+quad*4 .. +3
        rs += (e0 + e1) + (e2 + e3);
      }
      rs += bperm_f(ix16, rs);
      rs += bperm_f(ix32, rs);
      l_i[h2] = l_i[h2] * alpha + rs;
      m_i[h2] = mnew;
      #pragma unroll
      for (int dt = 0; dt < 4; ++dt) {
        oacc[h2][dt][0] *= alpha; oacc[h2][dt][1] *= alpha;
        oacc[h2][dt][2] *= alpha; oacc[h2][dt][3] *= alpha;
      }
    }
    asm volatile("s_waitcnt lgkmcnt(0)" ::: "memory");   // Ps visible (same wave)

    // ---- PV swapped: oacc[h2][dt] = O^T fragments; V/Ps reads as v5 ----
    #pragma unroll
    for (int ks = 0; ks < 4; ++ks) {
      const short* pr = Psw + l16 * 128 + (((ks * 4 + quad) ^ (l16 & 7)) * 8);
      bf16x8 ps0 = *(const bf16x8*)pr;
      bf16x8 ps1 = *(const bf16x8*)(pr + 2048);
      #pragma unroll
      for (int dt = 0; dt < 4; ++dt) {
        bf16x8 bb = *(const bf16x8*)&VtL[(dt * 16 + l16) * 128 +
                                         (((ks * 4 + quad) ^ (l16 & 7)) * 8)];
        oacc[0][dt] = __builtin_amdgcn_mfma_f32_16x16x32_bf16(bb, ps0, oacc[0][dt], 0, 0, 0);
        oacc[1][dt] = __builtin_amdgcn_mfma_f32_16x16x32_bf16(bb, ps1, oacc[1][dt], 0, 0, 0);
      }
    }
  }

  // ---- epilogue: O^T[d = dt*16+quad*4+r][q = l16-keyed]; pack d-pairs ----
  #pragma unroll
  for (int h2 = 0; h2 < 2; ++h2) {
    int q = q0 + wave * 32 + h2 * 16 + l16;
    float mk = maskbuf[((size_t)(b * NHEAD + h)) * S_LEN + q];
    float sc = mk / l_i[h2];
    short* dst = QpOg + (size_t)q * rstride + colbase;
    #pragma unroll
    for (int dt = 0; dt < 4; ++dt) {
      #pragma unroll
      for (int p = 0; p < 2; ++p) {
        unsigned lo = (unsigned short)f2bf(oacc[h2][dt][2*p]     * sc);
        unsigned hi = (unsigned short)f2bf(oacc[h2][dt][2*p + 1] * sc);
        *(unsigned*)(dst + dt*16 + quad*4 + 2*p) = lo | (hi << 16);
      }
    }
  }
}

// ---------------- kernel 5: out projection ----------------
// v2: 128x64 tiles (grid 32x16 = 512 blocks = 2/CU) instead of 128x128 @ 256
// blocks = 1 block/CU. Trades some per-block staging efficiency for 2x
// machine occupancy on this grid-starved dispatch.
__global__ __launch_bounds__(256) void gemm_out(
    const short* __restrict__ A, const short* __restrict__ W,
    const float* __restrict__ bias, float* __restrict__ out)
{
  __shared__ __attribute__((aligned(16))) short smem[6144];   // A 8K + B 4K bytes
  short* As = smem;              // 128*32
  short* Bs = smem + 4096;       // 64*32
  const int tid  = threadIdx.x;
  const int wave = tid >> 6, lane = tid & 63;
  const int quad = lane >> 4, l16 = lane & 15;
  const int wr = wave >> 1, wc = wave & 1;
  const int lr = lane >> 2, lc8 = (lane & 3) * 8;
  const int row0 = blockIdx.x * 128, col0 = blockIdx.y * 64;

  const short* gA = A + (size_t)(row0 + wave*16 + lr) * EDIM + lc8;
  const short* gB = W + (size_t)(col0 + wave*16 + lr) * EDIM + lc8;
  short* lA = As + wave*512;
  short* lB = Bs + wave*512;

  f32x4 acc[4][2] = {};
  gl_lds16(gA, lA);  gl_lds16(gA + 64*EDIM, lA + 64*32);
  gl_lds16(gB, lB);

  for (int k0 = 0; k0 < EDIM; k0 += 32) {
    __syncthreads();
    bf16x8 af[4], bfr[2];
    #pragma unroll
    for (int i = 0; i < 4; ++i)
      af[i] = *(const bf16x8*)&As[(wr*64 + i*16 + l16)*32 + quad*8];
    #pragma unroll
    for (int j = 0; j < 2; ++j)
      bfr[j] = *(const bf16x8*)&Bs[(wc*32 + j*16 + l16)*32 + quad*8];
    __syncthreads();
    if (k0 + 32 < EDIM) {
      const short* gA2 = gA + k0 + 32;
      gl_lds16(gA2, lA);  gl_lds16(gA2 + 64*EDIM, lA + 64*32);
      gl_lds16(gB + k0 + 32, lB);
    }
    #pragma unroll
    for (int i = 0; i < 4; ++i)
      #pragma unroll
      for (int j = 0; j < 2; ++j)
        acc[i][j] = __builtin_amdgcn_mfma_f32_16x16x32_bf16(af[i], bfr[j], acc[i][j], 0, 0, 0);
  }
  #pragma unroll
  for (int j = 0; j < 2; ++j) {
    int col = col0 + wc*32 + j*16 + l16;
    float bv = bias[col];
    #pragma unroll
    for (int i = 0; i < 4; ++i) {
      int rowb = row0 + wr*64 + i*16 + quad*4;
      #pragma unroll
      for (int r = 0; r < 4; ++r)
        out[(size_t)(rowb + r) * EDIM + col] = acc[i][j][r] + bv;
    }
  }
}

extern "C" void kernel_launch(void* const* d_in, const int* in_sizes, int n_in,
                              void* d_out, int out_size, void* d_ws, size_t ws_size,
                              hipStream_t stream)
{
  const float* query   = (const float*)d_in[0];
  const float* q_w     = (const float*)d_in[1];
  const float* q_b     = (const float*)d_in[2];
  const float* k_w     = (const float*)d_in[3];
  const float* k_b     = (const float*)d_in[4];
  const float* v_w     = (const float*)d_in[5];
  const float* v_b     = (const float*)d_in[6];
  const float* out_w   = (const float*)d_in[7];
  const float* out_b   = (const float*)d_in[8];
  const float* inf1_w  = (const float*)d_in[9];
  const float* inf1_b  = (const float*)d_in[10];
  const float* inf2_w  = (const float*)d_in[11];
  const float* inf2_b  = (const float*)d_in[12];
  const float* head_sig= (const float*)d_in[13];

  char* ws = (char*)d_ws;
  short* qh      = (short*)(ws);
  short* VTb     = (short*)(ws);
  short* ql      = (short*)(ws + (size_t)( 8u<<20));
  float* maskbuf = (float*)(ws + (size_t)( 8u<<20));
  short* Qp      = (short*)(ws + (size_t)(16u<<20));
  short* Kp      = (short*)(ws + (size_t)(24u<<20));
  short* Vp      = (short*)(ws + (size_t)(32u<<20));
  short* Wo      = (short*)(ws + (size_t)(40u<<20));
  char* ob = (char*)d_out;
  float* T1  = (float*)(ob);
  short* w1h = (short*)(ob + (size_t)( 8u<<20));
  short* w1l = (short*)(ob + (size_t)( 9u<<20));
  short* Wq  = (short*)(ob + (size_t)(10u<<20));
  short* Wk  = (short*)(ob + (size_t)(12u<<20));
  short* Wv  = (short*)(ob + (size_t)(14u<<20));
  float* out = (float*)d_out;

  dim3 blk(256);
  cvt_all<<<dim3(8704), blk, 0, stream>>>(query, inf1_w, q_w, k_w, v_w, out_w,
                                          qh, ql, w1h, w1l, Wq, Wk, Wv, Wo);
  mega_gemm1<<<dim3(1024), blk, 0, stream>>>(qh, ql, w1h, w1l, inf1_b, T1,
                                             Wq, Wk, Wv, q_b, k_b, v_b, Qp, Kp, Vp);
  mid_kernel<<<dim3(1536), blk, 0, stream>>>(T1, inf2_w, inf2_b, head_sig, maskbuf,
                                             Vp, VTb);
  flash_attn<<<dim3(32, 16), blk, 0, stream>>>(Qp, Kp, VTb, maskbuf);
  gemm_out<<<dim3(32, 16), blk, 0, stream>>>(Qp, Wo, out_b, out);
}

// Round 7
// 297.393 us; speedup vs baseline: 1.2140x; 1.0181x over previous
//
#include <hip/hip_runtime.h>
#include <hip/hip_bf16.h>

#define S_LEN 2048
#define BATCH 2
#define EDIM 1024
#define NHEAD 16
#define DHEAD 64
#define HIDDEN 512
#define SIGD 64
#define KEEP 12           // NUM_HEADS - INACTIVE

typedef __attribute__((ext_vector_type(8))) short bf16x8;
typedef __attribute__((ext_vector_type(4))) float f32x4;

static __device__ __forceinline__ float bf2f(short s) {
  unsigned int u = ((unsigned int)(unsigned short)s) << 16;
  float f; __builtin_memcpy(&f, &u, 4); return f;
}
static __device__ __forceinline__ short f2bf(float f) {
  unsigned int u; __builtin_memcpy(&u, &f, 4);
  u += 0x7fffu + ((u >> 16) & 1u);   // round-to-nearest-even
  return (short)(u >> 16);
}

#if __has_builtin(__builtin_amdgcn_exp2f)
static __device__ __forceinline__ float fexp2(float x) { return __builtin_amdgcn_exp2f(x); }
#else
static __device__ __forceinline__ float fexp2(float x) { return exp2f(x); }
#endif

// async global->LDS, 16B per lane. LDS dest is wave-uniform base + lane*16.
static __device__ __forceinline__ void gl_lds16(const short* g, short* l) {
  __builtin_amdgcn_global_load_lds(
      (const __attribute__((address_space(1))) unsigned int*)g,
      (__attribute__((address_space(3))) unsigned int*)l, 16, 0, 0);
}

static __device__ __forceinline__ float bperm_f(int idx, float v) {
  return __builtin_bit_cast(float,
      __builtin_amdgcn_ds_bpermute(idx, __builtin_bit_cast(int, v)));
}

// ---------------- kernel 1: ALL dtype conversions in one launch ----------------
// [0,4096): query hi/lo split. [4096,4608): inf1_w hi/lo split.
// [4608,5632) Wq, [5632,6656) Wk, [6656,7680) Wv, [7680,8704) Wo (plain bf16).
__global__ __launch_bounds__(256) void cvt_all(
    const float* __restrict__ query, const float* __restrict__ inf1_w,
    const float* __restrict__ qw, const float* __restrict__ kw,
    const float* __restrict__ vw, const float* __restrict__ ow,
    short* __restrict__ qh, short* __restrict__ ql,
    short* __restrict__ w1h, short* __restrict__ w1l,
    short* __restrict__ Wq, short* __restrict__ Wk,
    short* __restrict__ Wv, short* __restrict__ Wo)
{
  int blk = blockIdx.x;
  if (blk < 4608) {              // split sections
    const float* in; short *oh, *ol; int i;
    if (blk < 4096) { in = query;  oh = qh;  ol = ql;  i = (blk * 256 + threadIdx.x) * 4; }
    else            { in = inf1_w; oh = w1h; ol = w1l; i = ((blk - 4096) * 256 + threadIdx.x) * 4; }
    float4 f = *(const float4*)(in + i);
    union { short s[4]; uint2 v; } uh, ul;
    float x[4] = {f.x, f.y, f.z, f.w};
    #pragma unroll
    for (int u = 0; u < 4; ++u) {
      short h = f2bf(x[u]);
      uh.s[u] = h;
      ul.s[u] = f2bf(x[u] - bf2f(h));
    }
    *(uint2*)(oh + i) = uh.v;
    *(uint2*)(ol + i) = ul.v;
  } else {                       // plain bf16 sections (1024 blocks each)
    int t = blk - 4608;
    int mat = t >> 10, sub = t & 1023;
    const float* in = (mat == 0) ? qw : (mat == 1) ? kw : (mat == 2) ? vw : ow;
    short* out      = (mat == 0) ? Wq : (mat == 1) ? Wk : (mat == 2) ? Wv : Wo;
    int i = (sub * 256 + threadIdx.x) * 4;
    float4 f = *(const float4*)(in + i);
    union { short s[4]; uint2 v; } u;
    u.s[0] = f2bf(f.x); u.s[1] = f2bf(f.y); u.s[2] = f2bf(f.z); u.s[3] = f2bf(f.w);
    *(uint2*)(out + i) = u.v;
  }
}

// ---------------- m97-style 128x128 GEMM body (smem passed in) ----------------
// VTOUT=false: row-major bf16 out (Q/K).  VTOUT=true: V path -- write the
// transposed VT layout directly: VT[(b*1024 + col)][s] with t = row, b = t&1,
// s = t>>1. acc r-quadruple spans (b,s) as (0,S0),(1,S0),(0,S0+1),(1,S0+1) ->
// pack (r0,r2) and (r1,r3) into two b32 stores. Each VT 128B line is fully
// assembled within this block (s-range = exactly 64 shorts).
template<bool VTOUT>
static __device__ __forceinline__ void gemm128_body(
    short* smem,
    const short* __restrict__ A, const short* __restrict__ B,
    const float* __restrict__ bias, short* __restrict__ outv,
    int row0, int col0, float scale)
{
  short* As = smem;              // 128*32
  short* Bs = smem + 128*32;     // 128*32
  const int tid  = threadIdx.x;
  const int wave = tid >> 6, lane = tid & 63;
  const int quad = lane >> 4, l16 = lane & 15;
  const int wr = wave >> 1, wc = wave & 1;
  const int lr = lane >> 2, lc8 = (lane & 3) * 8;

  const short* gA = A + (size_t)(row0 + wave*16 + lr) * EDIM + lc8;
  const short* gB = B + (size_t)(col0 + wave*16 + lr) * EDIM + lc8;
  short* lA = As + wave*512;
  short* lB = Bs + wave*512;

  f32x4 acc[4][4] = {};
  gl_lds16(gA, lA);  gl_lds16(gA + 64*EDIM, lA + 64*32);
  gl_lds16(gB, lB);  gl_lds16(gB + 64*EDIM, lB + 64*32);

  for (int k0 = 0; k0 < EDIM; k0 += 32) {
    __syncthreads();
    bf16x8 af[4], bfr[4];
    #pragma unroll
    for (int i = 0; i < 4; ++i)
      af[i] = *(const bf16x8*)&As[(wr*64 + i*16 + l16)*32 + quad*8];
    #pragma unroll
    for (int j = 0; j < 4; ++j)
      bfr[j] = *(const bf16x8*)&Bs[(wc*64 + j*16 + l16)*32 + quad*8];
    __syncthreads();
    if (k0 + 32 < EDIM) {
      const short* gA2 = gA + k0 + 32;
      const short* gB2 = gB + k0 + 32;
      gl_lds16(gA2, lA);  gl_lds16(gA2 + 64*EDIM, lA + 64*32);
      gl_lds16(gB2, lB);  gl_lds16(gB2 + 64*EDIM, lB + 64*32);
    }
    #pragma unroll
    for (int i = 0; i < 4; ++i)
      #pragma unroll
      for (int j = 0; j < 4; ++j)
        acc[i][j] = __builtin_amdgcn_mfma_f32_16x16x32_bf16(af[i], bfr[j], acc[i][j], 0, 0, 0);
  }
  #pragma unroll
  for (int j = 0; j < 4; ++j) {
    int col = col0 + wc*64 + j*16 + l16;
    float bv = bias[col];
    #pragma unroll
    for (int i = 0; i < 4; ++i) {
      if constexpr (VTOUT) {
        int T0 = row0 + wr*64 + i*16 + quad*4;   // even token row
        int S0 = T0 >> 1;
        unsigned w0 = (unsigned short)f2bf(acc[i][j][0] + bv)
                    | ((unsigned)(unsigned short)f2bf(acc[i][j][2] + bv) << 16);
        unsigned w1 = (unsigned short)f2bf(acc[i][j][1] + bv)
                    | ((unsigned)(unsigned short)f2bf(acc[i][j][3] + bv) << 16);
        *(unsigned*)(outv + (size_t)col          * S_LEN + S0) = w0;   // b=0
        *(unsigned*)(outv + (size_t)(1024 + col) * S_LEN + S0) = w1;   // b=1
      } else {
        int rowb = row0 + wr*64 + i*16 + quad*4;
        #pragma unroll
        for (int r = 0; r < 4; ++r) {
          float v = (acc[i][j][r] + bv) * scale;
          outv[(size_t)(rowb + r) * EDIM + col] = f2bf(v);
        }
      }
    }
  }
}

// t1 body: 128x64 tile, hi/lo-split (3 MFMAs, fp32-accurate), relu -> T1 fp32.
static __device__ __forceinline__ void gemm_t1_body(
    short* smem,
    const short* __restrict__ Agh, const short* __restrict__ Agl,
    const short* __restrict__ Bgh, const short* __restrict__ Bgl,
    const float* __restrict__ bias, float* __restrict__ T1,
    int row0, int col0)
{
  short* Ah = smem;              // 128*32
  short* Al = smem + 4096;      // 128*32
  short* Bh = smem + 8192;      // 64*32
  short* Bl = smem + 10240;     // 64*32
  const int tid  = threadIdx.x;
  const int wave = tid >> 6, lane = tid & 63;
  const int quad = lane >> 4, l16 = lane & 15;
  const int wr = wave >> 1, wc = wave & 1;
  const int lr = lane >> 2, lc8 = (lane & 3) * 8;

  const short* gAh = Agh + (size_t)(row0 + wave*16 + lr) * EDIM + lc8;
  const short* gAl = Agl + (size_t)(row0 + wave*16 + lr) * EDIM + lc8;
  const short* gBh = Bgh + (size_t)(col0 + wave*16 + lr) * EDIM + lc8;
  const short* gBl = Bgl + (size_t)(col0 + wave*16 + lr) * EDIM + lc8;
  short* lAh = Ah + wave*512;  short* lAl = Al + wave*512;
  short* lBh = Bh + wave*512;  short* lBl = Bl + wave*512;

  f32x4 acc[4][2] = {};
  gl_lds16(gAh, lAh);  gl_lds16(gAh + 64*EDIM, lAh + 64*32);
  gl_lds16(gAl, lAl);  gl_lds16(gAl + 64*EDIM, lAl + 64*32);
  gl_lds16(gBh, lBh);  gl_lds16(gBl, lBl);

  for (int k0 = 0; k0 < EDIM; k0 += 32) {
    __syncthreads();
    bf16x8 ah[4], al[4], bh[2], bl[2];
    #pragma unroll
    for (int i = 0; i < 4; ++i) {
      ah[i] = *(const bf16x8*)&Ah[(wr*64 + i*16 + l16)*32 + quad*8];
      al[i] = *(const bf16x8*)&Al[(wr*64 + i*16 + l16)*32 + quad*8];
    }
    #pragma unroll
    for (int j = 0; j < 2; ++j) {
      bh[j] = *(const bf16x8*)&Bh[(wc*32 + j*16 + l16)*32 + quad*8];
      bl[j] = *(const bf16x8*)&Bl[(wc*32 + j*16 + l16)*32 + quad*8];
    }
    __syncthreads();
    if (k0 + 32 < EDIM) {
      const short* p;
      p = gAh + k0 + 32;  gl_lds16(p, lAh);  gl_lds16(p + 64*EDIM, lAh + 64*32);
      p = gAl + k0 + 32;  gl_lds16(p, lAl);  gl_lds16(p + 64*EDIM, lAl + 64*32);
      gl_lds16(gBh + k0 + 32, lBh);  gl_lds16(gBl + k0 + 32, lBl);
    }
    #pragma unroll
    for (int i = 0; i < 4; ++i)
      #pragma unroll
      for (int j = 0; j < 2; ++j) {
        acc[i][j] = __builtin_amdgcn_mfma_f32_16x16x32_bf16(ah[i], bh[j], acc[i][j], 0, 0, 0);
        acc[i][j] = __builtin_amdgcn_mfma_f32_16x16x32_bf16(ah[i], bl[j], acc[i][j], 0, 0, 0);
        acc[i][j] = __builtin_amdgcn_mfma_f32_16x16x32_bf16(al[i], bh[j], acc[i][j], 0, 0, 0);
      }
  }
  #pragma unroll
  for (int j = 0; j < 2; ++j) {
    int col = col0 + wc*32 + j*16 + l16;
    float bv = bias[col];
    #pragma unroll
    for (int i = 0; i < 4; ++i) {
      int rowb = row0 + wr*64 + i*16 + quad*4;
      #pragma unroll
      for (int r = 0; r < 4; ++r)
        T1[(size_t)(rowb + r) * HIDDEN + col] = fmaxf(acc[i][j][r] + bv, 0.0f);
    }
  }
}

// ---------------- kernel 2: t1 GEMM + QKV GEMM, interleaved 1:3 ----------------
// V blocks write the transposed VT layout directly (no Vp, no transpose kernel).
__global__ __launch_bounds__(256, 4) void mega_gemm1(
    const short* __restrict__ qh, const short* __restrict__ ql,
    const short* __restrict__ w1h, const short* __restrict__ w1l,
    const float* __restrict__ inf1_b, float* __restrict__ T1,
    const short* __restrict__ Wq, const short* __restrict__ Wk,
    const short* __restrict__ Wv,
    const float* __restrict__ qb, const float* __restrict__ kb,
    const float* __restrict__ vb,
    short* __restrict__ Qp, short* __restrict__ Kp, short* __restrict__ VT)
{
  __shared__ __attribute__((aligned(16))) short smem[12288];   // 24 KB union
  int blk = blockIdx.x;
  if ((blk & 3) == 3) {
    int id = blk >> 2;                         // [0,256)
    gemm_t1_body(smem, qh, ql, w1h, w1l, inf1_b, T1,
                 (id & 31) * 128, (id >> 5) * 64);
  } else {
    int id = (blk >> 2) * 3 + (blk & 3);       // [0,768)
    int row0 = (id & 31) * 128;
    int rest = id >> 5;                        // [0,24)
    int mat = rest >> 3, cb = rest & 7;
    if (mat == 2) {
      gemm128_body<true>(smem, qh, Wv, vb, VT, row0, cb * 128, 1.0f);
    } else {
      const short* B   = (mat == 0) ? Wq : Wk;
      const float* bia = (mat == 0) ? qb : kb;
      short* out       = (mat == 0) ? Qp : Kp;
      // q scale folds D^-0.5 * log2(e) (flash softmax runs in exp2 domain)
      float scale      = (mat == 0) ? 0.18033688011112042f : 1.0f;
      gemm128_body<false>(smem, qh, B, bia, out, row0, cb * 128, scale);
    }
  }
}

// ---------------- kernel 3: head-mask only (V transpose moved into mega) ----------------
__global__ __launch_bounds__(256) void mid_kernel(
    const float* __restrict__ T1, const float* __restrict__ inf2_w,
    const float* __restrict__ inf2_b, const float* __restrict__ head_sig,
    float* __restrict__ maskbuf)
{
  __shared__ __attribute__((aligned(16))) float fsm[8*HIDDEN + 8*SIGD + 8*NHEAD];
  const int g = blockIdx.x;                   // [0,512)
  const int tid = threadIdx.x;
  float (*t1s)[HIDDEN] = (float(*)[HIDDEN])fsm;
  float (*t2s)[SIGD]   = (float(*)[SIGD])(fsm + 8*HIDDEN);
  float (*ss)[NHEAD]   = (float(*)[NHEAD])(fsm + 8*HIDDEN + 8*SIGD);
  const int tok0 = g * 8;
  {
    int row = tid >> 5, c0 = (tid & 31) * 16;
    const float* src = T1 + (size_t)(tok0 + row) * HIDDEN + c0;
    #pragma unroll
    for (int u = 0; u < 4; ++u)
      *(float4*)&t1s[row][c0 + u*4] = *(const float4*)(src + u*4);
  }
  __syncthreads();
  {
    int tok = tid >> 5, j0 = (tid & 31) * 2;
    const float4* w0 = (const float4*)(inf2_w + (size_t)j0 * HIDDEN);
    const float4* w1 = (const float4*)(inf2_w + (size_t)(j0 + 1) * HIDDEN);
    const float4* t4 = (const float4*)(&t1s[tok][0]);
    float a0 = inf2_b[j0], a1 = inf2_b[j0 + 1];
    for (int k = 0; k < HIDDEN/4; ++k) {
      float4 tv = t4[k];
      float4 v0 = w0[k], v1 = w1[k];
      a0 += tv.x*v0.x + tv.y*v0.y + tv.z*v0.z + tv.w*v0.w;
      a1 += tv.x*v1.x + tv.y*v1.y + tv.z*v1.z + tv.w*v1.w;
    }
    t2s[tok][j0] = a0; t2s[tok][j0 + 1] = a1;
  }
  __syncthreads();
  if (tid < 128) {
    int tok = tid >> 4, h = tid & 15;
    float a = 0.f;
    for (int d = 0; d < SIGD; ++d) a += t2s[tok][d] * head_sig[h*SIGD + d];
    ss[tok][h] = a;
  }
  __syncthreads();
  if (tid < 128) {
    int tok = tid >> 4, h = tid & 15;
    float sv = ss[tok][h];
    int cnt = 0;
    #pragma unroll
    for (int j = 0; j < NHEAD; ++j) cnt += (ss[tok][j] > sv) ? 1 : 0;
    int gt = tok0 + tok;
    int s = gt >> 1, b = gt & 1;             // token row = s*B + b
    maskbuf[((size_t)(b*NHEAD + h)) * S_LEN + s] = (cnt < KEEP) ? 1.0f : 0.0f;
  }
}

// ---------------- kernel 4: flash attention (exp2 domain) ----------------
// v6 (unchanged): swapped-operand MFMAs, per-lane softmax, gl_lds staging
// with XOR-swizzled source, 64KB LDS, grid 512 = 2/CU zero-tail.
__global__ __launch_bounds__(256) void flash_attn(
    short* QpOg, const short* __restrict__ Kp, const short* __restrict__ VT,
    const float* __restrict__ maskbuf)
{
  __shared__ __attribute__((aligned(16))) short smem[32768];   // 64 KB exactly
  short* KsL = smem;            // [128 kv][64 d]   linear, chunk^=(row&7)
  short* VtL = smem + 8192;     // [64 d][128 kv]   linear, chunk^=(row&7)
  short* PsB = smem + 16384;    // 4 waves x [2 h2][16 q][128 kv], chunk^=(q&7)
  short* Qs  = smem + 16384;    // [128 q][64 d] union with Ps (pre-loop only)

  const int bh = blockIdx.x;
  const int b = bh >> 4, h = bh & 15;
  const int q0 = blockIdx.y * 128;
  const int tid = threadIdx.x;
  const int wave = tid >> 6, lane = tid & 63;
  const int quad = lane >> 4, l16 = lane & 15;
  const size_t colbase = (size_t)b * EDIM + h * DHEAD;
  const size_t rstride = (size_t)BATCH * EDIM;   // 2048
  short* Psw = PsB + wave * 4096;

  const int ix16 = (lane ^ 16) << 2;             // bpermute byte indices
  const int ix32 = (lane ^ 32) << 2;

  {  // ---- stage Q (swizzled), once ----
    int row = tid >> 1;
    int cb  = (tid & 1) * 4;
    const short* src = QpOg + (size_t)(q0 + row) * rstride + colbase + cb * 8;
    #pragma unroll
    for (int u = 0; u < 4; ++u) {
      uint4 v = *(const uint4*)(src + u * 8);
      *(uint4*)&Qs[row * 64 + (((cb + u) ^ (row & 7)) * 8)] = v;
    }
  }
  __syncthreads();
  bf16x8 aq[2][2];
  #pragma unroll
  for (int h2 = 0; h2 < 2; ++h2)
    #pragma unroll
    for (int dh = 0; dh < 2; ++dh) {
      int row = wave * 32 + h2 * 16 + l16;       // row&7 == l16&7
      aq[h2][dh] = *(const bf16x8*)&Qs[row * 64 + (((dh * 4 + quad) ^ (l16 & 7)) * 8)];
    }

  // staging lane constants
  const int kxor = (lane & 7) ^ (lane >> 3);      // K: chunk ^ row&7
  const short* gKbase = Kp + colbase + (size_t)(wave * 32 + (lane >> 3)) * rstride + kxor * 8;
  short* ldsK = KsL + wave * 2048;
  const int vrow_l = lane >> 4;
  short* ldsV = VtL + wave * 2048;

  float m_i[2] = {-1e30f, -1e30f};
  float l_i[2] = {0.f, 0.f};
  f32x4 oacc[2][4];
  #pragma unroll
  for (int h2 = 0; h2 < 2; ++h2)
    #pragma unroll
    for (int dt = 0; dt < 4; ++dt) oacc[h2][dt] = f32x4{0.f, 0.f, 0.f, 0.f};

  for (int kv0 = 0; kv0 < S_LEN; kv0 += 128) {
    __syncthreads();                 // all waves done reading previous tile
    #pragma unroll
    for (int i = 0; i < 4; ++i) {
      gl_lds16(gKbase + (size_t)(kv0 + i * 8) * rstride, ldsK + i * 512);
      int vrow = wave * 16 + i * 4 + vrow_l;
      int vx = (lane & 15) ^ ((i & 1) * 4 + vrow_l);
      gl_lds16(VT + (size_t)(bh * 64 + vrow) * S_LEN + kv0 + vx * 8, ldsV + i * 512);
    }
    asm volatile("s_waitcnt vmcnt(0)" ::: "memory");
    __syncthreads();                 // staged tile visible to all waves

    // ---- QK^T swapped: sacc[h2][c][r] = S^T[kv=c*16+quad*4+r][q=h2-set l16] ----
    f32x4 sacc[2][8];
    #pragma unroll
    for (int h2 = 0; h2 < 2; ++h2)
      #pragma unroll
      for (int c = 0; c < 8; ++c) sacc[h2][c] = f32x4{0.f, 0.f, 0.f, 0.f};
    #pragma unroll
    for (int c = 0; c < 8; ++c) {
      const short* kr = &KsL[(c * 16 + l16) * 64];          // row&7 == l16&7
      bf16x8 k0 = *(const bf16x8*)&kr[((quad     ^ (l16 & 7)) * 8)];
      bf16x8 k1 = *(const bf16x8*)&kr[(((4 + quad) ^ (l16 & 7)) * 8)];
      #pragma unroll
      for (int h2 = 0; h2 < 2; ++h2) {
        sacc[h2][c] = __builtin_amdgcn_mfma_f32_16x16x32_bf16(k0, aq[h2][0], sacc[h2][c], 0, 0, 0);
        sacc[h2][c] = __builtin_amdgcn_mfma_f32_16x16x32_bf16(k1, aq[h2][1], sacc[h2][c], 0, 0, 0);
      }
    }

    // ---- online softmax: per lane, one q-row per h2, 32 kv values in-lane ----
    #pragma unroll
    for (int h2 = 0; h2 < 2; ++h2) {
      float vm = fmaxf(fmaxf(sacc[h2][0][0], sacc[h2][0][1]),
                       fmaxf(sacc[h2][0][2], sacc[h2][0][3]));
      #pragma unroll
      for (int c = 1; c < 8; ++c)
        vm = fmaxf(vm, fmaxf(fmaxf(sacc[h2][c][0], sacc[h2][c][1]),
                             fmaxf(sacc[h2][c][2], sacc[h2][c][3])));
      vm = fmaxf(vm, bperm_f(ix16, vm));
      vm = fmaxf(vm, bperm_f(ix32, vm));
      float mnew = fmaxf(m_i[h2], vm);
      float alpha = fexp2(m_i[h2] - mnew);
      float rs = 0.f;
      short* pw = Psw + h2 * 2048 + l16 * 128 + (quad & 1) * 4;
      #pragma unroll
      for (int c = 0; c < 8; ++c) {
        float e0 = fexp2(sacc[h2][c][0] - mnew);
        float e1 = fexp2(sacc[h2][c][1] - mnew);
        float e2 = fexp2(sacc[h2][c][2] - mnew);
        float e3 = fexp2(sacc[h2][c][3] - mnew);
        unsigned lo = __builtin_amdgcn_perm(
            __builtin_bit_cast(unsigned, e1),
            __builtin_bit_cast(unsigned, e0), 0x07060302u);
        unsigned hi = __builtin_amdgcn_perm(
            __builtin_bit_cast(unsigned, e3),
            __builtin_bit_cast(unsigned, e2), 0x07060302u);
        int ch = (c * 2 + (quad >> 1)) ^ (l16 & 7);
        uint2 w2; w2.x = lo; w2.y = hi;
        *(uint2*)(pw + ch * 8) = w2;             // cols c*16+quad*4 .. +3
        rs += (e0 + e1) + (e2 + e3);
      }
      rs += bperm_f(ix16, rs);
      rs += bperm_f(ix32, rs);
      l_i[h2] = l_i[h2] * alpha + rs;
      m_i[h2] = mnew;
      #pragma unroll
      for (int dt = 0; dt < 4; ++dt) {
        oacc[h2][dt][0] *= alpha; oacc[h2][dt][1] *= alpha;
        oacc[h2][dt][2] *= alpha; oacc[h2][dt][3] *= alpha;
      }
    }
    asm volatile("s_waitcnt lgkmcnt(0)" ::: "memory");   // Ps visible (same wave)

    // ---- PV swapped: oacc[h2][dt] = O^T fragments ----
    #pragma unroll
    for (int ks = 0; ks < 4; ++ks) {
      const short* pr = Psw + l16 * 128 + (((ks * 4 + quad) ^ (l16 & 7)) * 8);
      bf16x8 ps0 = *(const bf16x8*)pr;
      bf16x8 ps1 = *(const bf16x8*)(pr + 2048);
      #pragma unroll
      for (int dt = 0; dt < 4; ++dt) {
        bf16x8 bb = *(const bf16x8*)&VtL[(dt * 16 + l16) * 128 +
                                         (((ks * 4 + quad) ^ (l16 & 7)) * 8)];
        oacc[0][dt] = __builtin_amdgcn_mfma_f32_16x16x32_bf16(bb, ps0, oacc[0][dt], 0, 0, 0);
        oacc[1][dt] = __builtin_amdgcn_mfma_f32_16x16x32_bf16(bb, ps1, oacc[1][dt], 0, 0, 0);
      }
    }
  }

  // ---- epilogue: O^T[d = dt*16+quad*4+r][q = l16-keyed]; pack d-pairs ----
  #pragma unroll
  for (int h2 = 0; h2 < 2; ++h2) {
    int q = q0 + wave * 32 + h2 * 16 + l16;
    float mk = maskbuf[((size_t)(b * NHEAD + h)) * S_LEN + q];
    float sc = mk / l_i[h2];
    short* dst = QpOg + (size_t)q * rstride + colbase;
    #pragma unroll
    for (int dt = 0; dt < 4; ++dt) {
      #pragma unroll
      for (int p = 0; p < 2; ++p) {
        unsigned lo = (unsigned short)f2bf(oacc[h2][dt][2*p]     * sc);
        unsigned hi = (unsigned short)f2bf(oacc[h2][dt][2*p + 1] * sc);
        *(unsigned*)(dst + dt*16 + quad*4 + 2*p) = lo | (hi << 16);
      }
    }
  }
}

// ---------------- kernel 5: out projection ----------------
__global__ __launch_bounds__(256) void gemm_out(
    const short* __restrict__ A, const short* __restrict__ W,
    const float* __restrict__ bias, float* __restrict__ out)
{
  __shared__ __attribute__((aligned(16))) short smem[6144];
  short* As = smem;              // 128*32
  short* Bs = smem + 4096;       // 64*32
  const int tid  = threadIdx.x;
  const int wave = tid >> 6, lane = tid & 63;
  const int quad = lane >> 4, l16 = lane & 15;
  const int wr = wave >> 1, wc = wave & 1;
  const int lr = lane >> 2, lc8 = (lane & 3) * 8;
  const int row0 = blockIdx.x * 128, col0 = blockIdx.y * 64;

  const short* gA = A + (size_t)(row0 + wave*16 + lr) * EDIM + lc8;
  const short* gB = W + (size_t)(col0 + wave*16 + lr) * EDIM + lc8;
  short* lA = As + wave*512;
  short* lB = Bs + wave*512;

  f32x4 acc[4][2] = {};
  gl_lds16(gA, lA);  gl_lds16(gA + 64*EDIM, lA + 64*32);
  gl_lds16(gB, lB);

  for (int k0 = 0; k0 < EDIM; k0 += 32) {
    __syncthreads();
    bf16x8 af[4], bfr[2];
    #pragma unroll
    for (int i = 0; i < 4; ++i)
      af[i] = *(const bf16x8*)&As[(wr*64 + i*16 + l16)*32 + quad*8];
    #pragma unroll
    for (int j = 0; j < 2; ++j)
      bfr[j] = *(const bf16x8*)&Bs[(wc*32 + j*16 + l16)*32 + quad*8];
    __syncthreads();
    if (k0 + 32 < EDIM) {
      const short* gA2 = gA + k0 + 32;
      gl_lds16(gA2, lA);  gl_lds16(gA2 + 64*EDIM, lA + 64*32);
      gl_lds16(gB + k0 + 32, lB);
    }
    #pragma unroll
    for (int i = 0; i < 4; ++i)
      #pragma unroll
      for (int j = 0; j < 2; ++j)
        acc[i][j] = __builtin_amdgcn_mfma_f32_16x16x32_bf16(af[i], bfr[j], acc[i][j], 0, 0, 0);
  }
  #pragma unroll
  for (int j = 0; j < 2; ++j) {
    int col = col0 + wc*32 + j*16 + l16;
    float bv = bias[col];
    #pragma unroll
    for (int i = 0; i < 4; ++i) {
      int rowb = row0 + wr*64 + i*16 + quad*4;
      #pragma unroll
      for (int r = 0; r < 4; ++r)
        out[(size_t)(rowb + r) * EDIM + col] = acc[i][j][r] + bv;
    }
  }
}

extern "C" void kernel_launch(void* const* d_in, const int* in_sizes, int n_in,
                              void* d_out, int out_size, void* d_ws, size_t ws_size,
                              hipStream_t stream)
{
  const float* query   = (const float*)d_in[0];
  const float* q_w     = (const float*)d_in[1];
  const float* q_b     = (const float*)d_in[2];
  const float* k_w     = (const float*)d_in[3];
  const float* k_b     = (const float*)d_in[4];
  const float* v_w     = (const float*)d_in[5];
  const float* v_b     = (const float*)d_in[6];
  const float* out_w   = (const float*)d_in[7];
  const float* out_b   = (const float*)d_in[8];
  const float* inf1_w  = (const float*)d_in[9];
  const float* inf1_b  = (const float*)d_in[10];
  const float* inf2_w  = (const float*)d_in[11];
  const float* inf2_b  = (const float*)d_in[12];
  const float* head_sig= (const float*)d_in[13];

  // ws layout:
  //  [0,8)   qh
  //  [8,16)  ql -> maskbuf after mega_gemm1
  //  [16,24) Qp (flash in-place gated O)
  //  [24,32) Kp
  //  [32,40) VT (written TRANSPOSED directly by mega_gemm1's V blocks)
  //  [40,42) Wo
  char* ws = (char*)d_ws;
  short* qh      = (short*)(ws);
  short* ql      = (short*)(ws + (size_t)( 8u<<20));
  float* maskbuf = (float*)(ws + (size_t)( 8u<<20));
  short* Qp      = (short*)(ws + (size_t)(16u<<20));
  short* Kp      = (short*)(ws + (size_t)(24u<<20));
  short* VTb     = (short*)(ws + (size_t)(32u<<20));
  short* Wo      = (short*)(ws + (size_t)(40u<<20));
  char* ob = (char*)d_out;
  float* T1  = (float*)(ob);
  short* w1h = (short*)(ob + (size_t)( 8u<<20));
  short* w1l = (short*)(ob + (size_t)( 9u<<20));
  short* Wq  = (short*)(ob + (size_t)(10u<<20));
  short* Wk  = (short*)(ob + (size_t)(12u<<20));
  short* Wv  = (short*)(ob + (size_t)(14u<<20));
  float* out = (float*)d_out;

  dim3 blk(256);
  cvt_all<<<dim3(8704), blk, 0, stream>>>(query, inf1_w, q_w, k_w, v_w, out_w,
                                          qh, ql, w1h, w1l, Wq, Wk, Wv, Wo);
  mega_gemm1<<<dim3(1024), blk, 0, stream>>>(qh, ql, w1h, w1l, inf1_b, T1,
                                             Wq, Wk, Wv, q_b, k_b, v_b, Qp, Kp, VTb);
  mid_kernel<<<dim3(512), blk, 0, stream>>>(T1, inf2_w, inf2_b, head_sig, maskbuf);
  flash_attn<<<dim3(32, 16), blk, 0, stream>>>(Qp, Kp, VTb, maskbuf);
  gemm_out<<<dim3(32, 16), blk, 0, stream>>>(Qp, Wo, out_b, out);
}